// Round 2
// baseline (2291.097 us; speedup 1.0000x reference)
//
#include <hip/hip_runtime.h>
#include <hip/hip_bf16.h>
#include <cstdio>

#define INV_SQRT_D 0.17677669529663687f

// ---------------------------------------------------------------- proj ----
__global__ __launch_bounds__(256) void proj_kernel(
    const float* __restrict__ xs, const float* __restrict__ xd,
    const float* __restrict__ xp, const float* __restrict__ xt,
    const float* __restrict__ W, float* __restrict__ x, int N)
{
    int idx = blockIdx.x * 256 + threadIdx.x;
    if (idx >= N * 128) return;
    int n = idx >> 7, c = idx & 127;
    const float* w = W + c;
    float acc = 0.f;
    const float* a = xs + (size_t)n * 22;
    #pragma unroll
    for (int k = 0; k < 22; ++k) acc += a[k] * w[(k) * 128];
    const float* b = xd + (size_t)n * 12;
    #pragma unroll
    for (int k = 0; k < 12; ++k) acc += b[k] * w[(22 + k) * 128];
    const float* p = xp + (size_t)n * 7;
    #pragma unroll
    for (int k = 0; k < 7; ++k) acc += p[k] * w[(34 + k) * 128];
    const float* t = xt + (size_t)n * 4;
    #pragma unroll
    for (int k = 0; k < 4; ++k) acc += t[k] * w[(41 + k) * 128];
    x[idx] = acc;
}

// ----------------------------------------------------------- CSR build ----
__global__ __launch_bounds__(256) void deg_kernel(
    const int* __restrict__ dst, int* __restrict__ deg, int E)
{
    int e = blockIdx.x * 256 + threadIdx.x;
    if (e < E) atomicAdd(&deg[dst[e]], 1);
}

__global__ __launch_bounds__(1024) void scan_kernel(
    const int* __restrict__ deg, int* __restrict__ row_start,
    int* __restrict__ cursor, int n)
{
    __shared__ int buf[2][1024];
    int t = threadIdx.x;
    int per = (n + 1023) >> 10;
    int start = t * per;
    int s = 0;
    for (int j = 0; j < per; ++j) {
        int idx = start + j;
        if (idx < n) s += deg[idx];
    }
    int x = s;
    buf[0][t] = x;
    __syncthreads();
    int sel = 0;
    for (int off = 1; off < 1024; off <<= 1) {
        int y = (t >= off) ? buf[sel][t - off] : 0;
        x += y;
        buf[sel ^ 1][t] = x;
        sel ^= 1;
        __syncthreads();
    }
    int run = x - s;  // exclusive prefix base
    for (int j = 0; j < per; ++j) {
        int idx = start + j;
        if (idx < n) {
            row_start[idx] = run;
            cursor[idx] = run;
            run += deg[idx];
        }
    }
    if (t == 1023) row_start[n] = x;
}

__global__ __launch_bounds__(256) void scatter_kernel(
    const int* __restrict__ src, const int* __restrict__ dst,
    int* __restrict__ cursor, int* __restrict__ col_src, int E)
{
    int e = blockIdx.x * 256 + threadIdx.x;
    if (e < E) {
        int d = dst[e];
        int pos = atomicAdd(&cursor[d], 1);
        col_src[pos] = src[e];
    }
}

// -------------------------------------------------- fused LN + 4x GEMM ----
// 16 rows/block, 256 threads. Outputs: q (f32), k (bf16), v (bf16), hs (f32)
__global__ __launch_bounds__(256) void lngemm_kernel(
    const float* __restrict__ x, const float* __restrict__ g, const float* __restrict__ bb,
    const float* __restrict__ Wq, const float* __restrict__ bq,
    const float* __restrict__ Wk, const float* __restrict__ bk,
    const float* __restrict__ Wv, const float* __restrict__ bv,
    const float* __restrict__ Ws, const float* __restrict__ bs,
    float* __restrict__ q, __hip_bfloat16* __restrict__ kb,
    __hip_bfloat16* __restrict__ vb, float* __restrict__ hs, int N)
{
    __shared__ float xsm[16][132];
    int t = threadIdx.x;
    int n0 = blockIdx.x * 16;
    int r = t >> 4, c8 = (t & 15) * 8;
    int row = n0 + r;
    float4 u0 = make_float4(0, 0, 0, 0), u1 = make_float4(0, 0, 0, 0);
    if (row < N) {
        const float* xr = x + (size_t)row * 128 + c8;
        u0 = *(const float4*)xr;
        u1 = *(const float4*)(xr + 4);
    }
    float s = u0.x + u0.y + u0.z + u0.w + u1.x + u1.y + u1.z + u1.w;
    float ss = u0.x * u0.x + u0.y * u0.y + u0.z * u0.z + u0.w * u0.w +
               u1.x * u1.x + u1.y * u1.y + u1.z * u1.z + u1.w * u1.w;
    #pragma unroll
    for (int off = 1; off < 16; off <<= 1) {
        s += __shfl_xor(s, off);
        ss += __shfl_xor(ss, off);
    }
    float mu = s * (1.f / 128.f);
    float var = ss * (1.f / 128.f) - mu * mu;
    float rs = rsqrtf(var + 1e-5f);
    float4 gv0 = *(const float4*)(g + c8);
    float4 gv1 = *(const float4*)(g + c8 + 4);
    float4 bv0 = *(const float4*)(bb + c8);
    float4 bv1 = *(const float4*)(bb + c8 + 4);
    xsm[r][c8 + 0] = (u0.x - mu) * rs * gv0.x + bv0.x;
    xsm[r][c8 + 1] = (u0.y - mu) * rs * gv0.y + bv0.y;
    xsm[r][c8 + 2] = (u0.z - mu) * rs * gv0.z + bv0.z;
    xsm[r][c8 + 3] = (u0.w - mu) * rs * gv0.w + bv0.w;
    xsm[r][c8 + 4] = (u1.x - mu) * rs * gv1.x + bv1.x;
    xsm[r][c8 + 5] = (u1.y - mu) * rs * gv1.y + bv1.y;
    xsm[r][c8 + 6] = (u1.z - mu) * rs * gv1.z + bv1.z;
    xsm[r][c8 + 7] = (u1.w - mu) * rs * gv1.w + bv1.w;
    __syncthreads();

    int cc = t & 127;
    const float* W0 = (t < 128) ? Wq : Wk;
    const float* W1 = (t < 128) ? Wv : Ws;
    float bias0 = ((t < 128) ? bq : bk)[cc];
    float bias1 = ((t < 128) ? bv : bs)[cc];
    float acc0[16], acc1[16];
    #pragma unroll
    for (int i = 0; i < 16; ++i) { acc0[i] = 0.f; acc1[i] = 0.f; }
    for (int k0 = 0; k0 < 128; k0 += 4) {
        float w00 = W0[(k0 + 0) * 128 + cc];
        float w01 = W0[(k0 + 1) * 128 + cc];
        float w02 = W0[(k0 + 2) * 128 + cc];
        float w03 = W0[(k0 + 3) * 128 + cc];
        float w10 = W1[(k0 + 0) * 128 + cc];
        float w11 = W1[(k0 + 1) * 128 + cc];
        float w12 = W1[(k0 + 2) * 128 + cc];
        float w13 = W1[(k0 + 3) * 128 + cc];
        #pragma unroll
        for (int rr = 0; rr < 16; ++rr) {
            float4 xv = *(const float4*)&xsm[rr][k0];
            acc0[rr] += xv.x * w00 + xv.y * w01 + xv.z * w02 + xv.w * w03;
            acc1[rr] += xv.x * w10 + xv.y * w11 + xv.z * w12 + xv.w * w13;
        }
    }
    if (t < 128) {
        #pragma unroll
        for (int rr = 0; rr < 16; ++rr) {
            int n = n0 + rr;
            if (n < N) {
                q[(size_t)n * 128 + cc] = acc0[rr] + bias0;
                vb[(size_t)n * 128 + cc] = __float2bfloat16(acc1[rr] + bias1);
            }
        }
    } else {
        #pragma unroll
        for (int rr = 0; rr < 16; ++rr) {
            int n = n0 + rr;
            if (n < N) {
                kb[(size_t)n * 128 + cc] = __float2bfloat16(acc0[rr] + bias0);
                hs[(size_t)n * 128 + cc] = acc1[rr] + bias1;
            }
        }
    }
}

// -------------------------------------------- per-node online attention ---
// one wave per dst node; lane owns channels 2l, 2l+1 (head = l/16)
// xin/xout separate so blocks 2 & 3 can branch off the same input.
// NOTE: xout may alias q (block 2): each wave reads q[n] before writing
// xout[n], same elements only -> safe; q/xout deliberately NOT __restrict__.
__global__ __launch_bounds__(256) void attn_kernel(
    const float* q, const unsigned short* __restrict__ kp,
    const unsigned short* __restrict__ vp, const float* __restrict__ hs,
    const int* __restrict__ row_start, const int* __restrict__ col_src,
    const float* __restrict__ xin, float* xout, int N)
{
    int wid = threadIdx.x >> 6, lane = threadIdx.x & 63;
    int n = blockIdx.x * 4 + wid;
    if (n >= N) return;
    int c = lane * 2;
    float2 qv = *(const float2*)&q[(size_t)n * 128 + c];
    int beg = row_start[n], end = row_start[n + 1];
    float m = -3.0e38f, den = 0.f, a0 = 0.f, a1 = 0.f;
    for (int i = beg; i < end; ++i) {
        int s = col_src[i];
        unsigned kk = *(const unsigned*)(kp + (size_t)s * 128 + c);
        float k0 = __uint_as_float((kk & 0xffffu) << 16);
        float k1 = __uint_as_float(kk & 0xffff0000u);
        float p = qv.x * k0 + qv.y * k1;
        p += __shfl_xor(p, 1);
        p += __shfl_xor(p, 2);
        p += __shfl_xor(p, 4);
        p += __shfl_xor(p, 8);
        float sc = p * INV_SQRT_D;
        float mn = fmaxf(m, sc);
        float corr = __expf(m - mn);
        float w = __expf(sc - mn);
        unsigned vv = *(const unsigned*)(vp + (size_t)s * 128 + c);
        float v0 = __uint_as_float((vv & 0xffffu) << 16);
        float v1 = __uint_as_float(vv & 0xffff0000u);
        den = den * corr + w;
        a0 = a0 * corr + w * v0;
        a1 = a1 * corr + w * v1;
        m = mn;
    }
    float inv = 1.f / (den + 1e-16f);
    float2 hv = *(const float2*)&hs[(size_t)n * 128 + c];
    float o0 = a0 * inv + hv.x;
    float o1 = a1 * inv + hv.y;
    o0 = o0 > 0.f ? o0 : 0.f;
    o1 = o1 > 0.f ? o1 : 0.f;
    float2 xv = *(const float2*)&xin[(size_t)n * 128 + c];
    xv.x += o0;
    xv.y += o1;
    *(float2*)&xout[(size_t)n * 128 + c] = xv;
}

// ------------------------------------------------------------- MLP head ---
// wave handles 4 rows: out = lrelu(x@fw+fb) @ ow + ob
__global__ __launch_bounds__(256) void head_kernel(
    const float* __restrict__ x, const float* __restrict__ fw,
    const float* __restrict__ fb, const float* __restrict__ ow,
    const float* __restrict__ ob, float* __restrict__ out, int OUTD, int N)
{
    int wid = threadIdx.x >> 6, lane = threadIdx.x & 63;
    int n0 = (blockIdx.x * 4 + wid) * 4;
    if (n0 >= N) return;
    float2 xr[4];
    #pragma unroll
    for (int j = 0; j < 4; ++j) {
        int n = n0 + j;
        xr[j] = (n < N) ? *(const float2*)&x[(size_t)n * 128 + lane * 2]
                        : make_float2(0.f, 0.f);
    }
    float acc[4][2];
    #pragma unroll
    for (int j = 0; j < 4; ++j) { acc[j][0] = 0.f; acc[j][1] = 0.f; }
    for (int k = 0; k < 128; ++k) {
        float w0 = fw[k * 128 + lane];
        float w1 = fw[k * 128 + 64 + lane];
        int srcl = k >> 1;
        #pragma unroll
        for (int j = 0; j < 4; ++j) {
            float xk = __shfl((k & 1) ? xr[j].y : xr[j].x, srcl);
            acc[j][0] += xk * w0;
            acc[j][1] += xk * w1;
        }
    }
    float b0 = fb[lane], b1 = fb[64 + lane];
    #pragma unroll
    for (int j = 0; j < 4; ++j) {
        int n = n0 + j;
        if (n >= N) break;  // wave-uniform
        float t0 = acc[j][0] + b0; t0 = (t0 > 0.f) ? t0 : 0.2f * t0;
        float t1 = acc[j][1] + b1; t1 = (t1 > 0.f) ? t1 : 0.2f * t1;
        for (int jo = 0; jo < OUTD; ++jo) {
            float p = t0 * ow[lane * OUTD + jo] + t1 * ow[(64 + lane) * OUTD + jo];
            p += __shfl_xor(p, 32);
            p += __shfl_xor(p, 16);
            p += __shfl_xor(p, 8);
            p += __shfl_xor(p, 4);
            p += __shfl_xor(p, 2);
            p += __shfl_xor(p, 1);
            if (lane == 0) out[(size_t)n * OUTD + jo] = p + ob[jo];
        }
    }
}

// ------------------------------------------------------------------ host --
static inline size_t align_up(size_t v, size_t a) { return (v + a - 1) & ~(a - 1); }

extern "C" void kernel_launch(void* const* d_in, const int* in_sizes, int n_in,
                              void* d_out, int out_size, void* d_ws, size_t ws_size,
                              hipStream_t stream)
{
    const float* xs = (const float*)d_in[0];
    const float* xd = (const float*)d_in[1];
    const float* xp = (const float*)d_in[2];
    const float* xt = (const float*)d_in[3];
    const int* edge = (const int*)d_in[4];
    const float* proj_w = (const float*)d_in[5];
    const float* ln_g = (const float*)d_in[6];
    const float* ln_b = (const float*)d_in[7];
    const float* Wq = (const float*)d_in[8];
    const float* bq = (const float*)d_in[9];
    const float* Wk = (const float*)d_in[10];
    const float* bk = (const float*)d_in[11];
    const float* Wv = (const float*)d_in[12];
    const float* bv = (const float*)d_in[13];
    const float* Ws = (const float*)d_in[14];
    const float* bs = (const float*)d_in[15];
    const float* fc1_w = (const float*)d_in[16];
    const float* fc1_b = (const float*)d_in[17];
    const float* fc2_w = (const float*)d_in[18];
    const float* fc2_b = (const float*)d_in[19];
    const float* fc3_w = (const float*)d_in[20];
    const float* fc3_b = (const float*)d_in[21];
    const float* fc4_w = (const float*)d_in[22];
    const float* fc4_b = (const float*)d_in[23];

    int N = in_sizes[0] / 22;
    int E = in_sizes[4] / 2;
    const int* srcp = edge;
    const int* dstp = edge + E;

    // workspace carve-up
    char* w = (char*)d_ws;
    size_t off = 0;
    auto take = [&](size_t bytes) {
        char* p = w + off;
        off = align_up(off + bytes, 256);
        return p;
    };
    float* x = (float*)take((size_t)N * 128 * 4);
    float* q = (float*)take((size_t)N * 128 * 4);
    float* hsb = (float*)take((size_t)N * 128 * 4);
    __hip_bfloat16* kb = (__hip_bfloat16*)take((size_t)N * 128 * 2);
    __hip_bfloat16* vb = (__hip_bfloat16*)take((size_t)N * 128 * 2);
    int* deg = (int*)take((size_t)N * 4);
    int* row_start = (int*)take((size_t)(N + 1) * 4);
    int* cursor = (int*)take((size_t)N * 4);
    int* col_src = (int*)take((size_t)E * 4);
    if (off > ws_size) {
        fprintf(stderr, "kernel_launch: ws too small (%zu > %zu)\n", off, ws_size);
        return;
    }

    float* out = (float*)d_out;

    // CSR build
    hipMemsetAsync(deg, 0, (size_t)N * 4, stream);
    deg_kernel<<<(E + 255) / 256, 256, 0, stream>>>(dstp, deg, E);
    scan_kernel<<<1, 1024, 0, stream>>>(deg, row_start, cursor, N);
    scatter_kernel<<<(E + 255) / 256, 256, 0, stream>>>(srcp, dstp, cursor, col_src, E);

    // input projection
    proj_kernel<<<((size_t)N * 128 + 255) / 256, 256, 0, stream>>>(
        xs, xd, xp, xt, proj_w, x, N);

    int gemm_blocks = (N + 15) / 16;
    int attn_blocks = (N + 3) / 4;
    int head_blocks = (N + 15) / 16;

    const unsigned short* kpu = (const unsigned short*)kb;
    const unsigned short* vpu = (const unsigned short*)vb;

    // block 0: x = blk(x, 0)
    lngemm_kernel<<<gemm_blocks, 256, 0, stream>>>(
        x, ln_g + 0 * 128, ln_b + 0 * 128,
        Wq + (size_t)0 * 16384, bq + 0 * 128, Wk + (size_t)0 * 16384, bk + 0 * 128,
        Wv + (size_t)0 * 16384, bv + 0 * 128, Ws + (size_t)0 * 16384, bs + 0 * 128,
        q, kb, vb, hsb, N);
    attn_kernel<<<attn_blocks, 256, 0, stream>>>(
        q, kpu, vpu, hsb, row_start, col_src, x, x, N);

    // block 1: x = blk(x, 1)
    lngemm_kernel<<<gemm_blocks, 256, 0, stream>>>(
        x, ln_g + 1 * 128, ln_b + 1 * 128,
        Wq + (size_t)1 * 16384, bq + 1 * 128, Wk + (size_t)1 * 16384, bk + 1 * 128,
        Wv + (size_t)1 * 16384, bv + 1 * 128, Ws + (size_t)1 * 16384, bs + 1 * 128,
        q, kb, vb, hsb, N);
    attn_kernel<<<attn_blocks, 256, 0, stream>>>(
        q, kpu, vpu, hsb, row_start, col_src, x, x, N);

    // block 2: x_pi = blk(x, 2) -> write result into q buffer (x stays intact)
    lngemm_kernel<<<gemm_blocks, 256, 0, stream>>>(
        x, ln_g + 2 * 128, ln_b + 2 * 128,
        Wq + (size_t)2 * 16384, bq + 2 * 128, Wk + (size_t)2 * 16384, bk + 2 * 128,
        Wv + (size_t)2 * 16384, bv + 2 * 128, Ws + (size_t)2 * 16384, bs + 2 * 128,
        q, kb, vb, hsb, N);
    attn_kernel<<<attn_blocks, 256, 0, stream>>>(
        q, kpu, vpu, hsb, row_start, col_src, x, q, N);  // xout = q = x_pi

    // prog head from x_pi (q buffer)
    head_kernel<<<head_blocks, 256, 0, stream>>>(
        q, fc1_w, fc1_b, fc3_w, fc3_b, out, 7, N);

    // block 3: x_dg = blk(x, 3) -- branches off the SAME post-block-1 x
    lngemm_kernel<<<gemm_blocks, 256, 0, stream>>>(
        x, ln_g + 3 * 128, ln_b + 3 * 128,
        Wq + (size_t)3 * 16384, bq + 3 * 128, Wk + (size_t)3 * 16384, bk + 3 * 128,
        Wv + (size_t)3 * 16384, bv + 3 * 128, Ws + (size_t)3 * 16384, bs + 3 * 128,
        q, kb, vb, hsb, N);
    attn_kernel<<<attn_blocks, 256, 0, stream>>>(
        q, kpu, vpu, hsb, row_start, col_src, x, x, N);

    // diag head from x_dg (x buffer)
    head_kernel<<<head_blocks, 256, 0, stream>>>(
        x, fc2_w, fc2_b, fc4_w, fc4_b, out + (size_t)N * 7, 3, N);
}

// Round 5
// 2045.999 us; speedup vs baseline: 1.1198x; 1.1198x over previous
//
#include <hip/hip_runtime.h>
#include <hip/hip_bf16.h>
#include <cstdio>

#define INV_SQRT_D 0.17677669529663687f

// ---------------------------------------------------------------- proj ----
__global__ __launch_bounds__(256) void proj_kernel(
    const float* __restrict__ xs, const float* __restrict__ xd,
    const float* __restrict__ xp, const float* __restrict__ xt,
    const float* __restrict__ W, float* __restrict__ x, int N)
{
    int idx = blockIdx.x * 256 + threadIdx.x;
    if (idx >= N * 128) return;
    int n = idx >> 7, c = idx & 127;
    const float* w = W + c;
    float acc = 0.f;
    const float* a = xs + (size_t)n * 22;
    #pragma unroll
    for (int k = 0; k < 22; ++k) acc += a[k] * w[(k) * 128];
    const float* b = xd + (size_t)n * 12;
    #pragma unroll
    for (int k = 0; k < 12; ++k) acc += b[k] * w[(22 + k) * 128];
    const float* p = xp + (size_t)n * 7;
    #pragma unroll
    for (int k = 0; k < 7; ++k) acc += p[k] * w[(34 + k) * 128];
    const float* t = xt + (size_t)n * 4;
    #pragma unroll
    for (int k = 0; k < 4; ++k) acc += t[k] * w[(41 + k) * 128];
    x[idx] = acc;
}

// ----------------------------------------------------------- CSR build ----
__global__ __launch_bounds__(256) void deg_kernel(
    const int* __restrict__ dst, int* __restrict__ deg, int E)
{
    int e = blockIdx.x * 256 + threadIdx.x;
    if (e < E) atomicAdd(&deg[dst[e]], 1);
}

__global__ __launch_bounds__(1024) void scan_kernel(
    const int* __restrict__ deg, int* __restrict__ row_start,
    int* __restrict__ cursor, int n)
{
    __shared__ int buf[2][1024];
    int t = threadIdx.x;
    int per = (n + 1023) >> 10;
    int start = t * per;
    int s = 0;
    for (int j = 0; j < per; ++j) {
        int idx = start + j;
        if (idx < n) s += deg[idx];
    }
    int x = s;
    buf[0][t] = x;
    __syncthreads();
    int sel = 0;
    for (int off = 1; off < 1024; off <<= 1) {
        int y = (t >= off) ? buf[sel][t - off] : 0;
        x += y;
        buf[sel ^ 1][t] = x;
        sel ^= 1;
        __syncthreads();
    }
    int run = x - s;  // exclusive prefix base
    for (int j = 0; j < per; ++j) {
        int idx = start + j;
        if (idx < n) {
            row_start[idx] = run;
            cursor[idx] = run;
            run += deg[idx];
        }
    }
    if (t == 1023) row_start[n] = x;
}

__global__ __launch_bounds__(256) void scatter_kernel(
    const int* __restrict__ src, const int* __restrict__ dst,
    int* __restrict__ cursor, int* __restrict__ col_src, int E)
{
    int e = blockIdx.x * 256 + threadIdx.x;
    if (e < E) {
        int d = dst[e];
        int pos = atomicAdd(&cursor[d], 1);
        col_src[pos] = src[e];
    }
}

// -------------------------------------------------- fused LN + 4x GEMM ----
// (round-2 proven version) 16 rows/block, 256 threads.
// Outputs: q (f32), k (bf16), v (bf16), hs (f32)
__global__ __launch_bounds__(256) void lngemm_kernel(
    const float* __restrict__ x, const float* __restrict__ g, const float* __restrict__ bb,
    const float* __restrict__ Wq, const float* __restrict__ bq,
    const float* __restrict__ Wk, const float* __restrict__ bk,
    const float* __restrict__ Wv, const float* __restrict__ bv,
    const float* __restrict__ Ws, const float* __restrict__ bs,
    float* __restrict__ q, __hip_bfloat16* __restrict__ kb,
    __hip_bfloat16* __restrict__ vb, float* __restrict__ hs, int N)
{
    __shared__ float xsm[16][132];
    int t = threadIdx.x;
    int n0 = blockIdx.x * 16;
    int r = t >> 4, c8 = (t & 15) * 8;
    int row = n0 + r;
    float4 u0 = make_float4(0, 0, 0, 0), u1 = make_float4(0, 0, 0, 0);
    if (row < N) {
        const float* xr = x + (size_t)row * 128 + c8;
        u0 = *(const float4*)xr;
        u1 = *(const float4*)(xr + 4);
    }
    float s = u0.x + u0.y + u0.z + u0.w + u1.x + u1.y + u1.z + u1.w;
    float ss = u0.x * u0.x + u0.y * u0.y + u0.z * u0.z + u0.w * u0.w +
               u1.x * u1.x + u1.y * u1.y + u1.z * u1.z + u1.w * u1.w;
    #pragma unroll
    for (int off = 1; off < 16; off <<= 1) {
        s += __shfl_xor(s, off);
        ss += __shfl_xor(ss, off);
    }
    float mu = s * (1.f / 128.f);
    float var = ss * (1.f / 128.f) - mu * mu;
    float rs = rsqrtf(var + 1e-5f);
    float4 gv0 = *(const float4*)(g + c8);
    float4 gv1 = *(const float4*)(g + c8 + 4);
    float4 bv0 = *(const float4*)(bb + c8);
    float4 bv1 = *(const float4*)(bb + c8 + 4);
    xsm[r][c8 + 0] = (u0.x - mu) * rs * gv0.x + bv0.x;
    xsm[r][c8 + 1] = (u0.y - mu) * rs * gv0.y + bv0.y;
    xsm[r][c8 + 2] = (u0.z - mu) * rs * gv0.z + bv0.z;
    xsm[r][c8 + 3] = (u0.w - mu) * rs * gv0.w + bv0.w;
    xsm[r][c8 + 4] = (u1.x - mu) * rs * gv1.x + bv1.x;
    xsm[r][c8 + 5] = (u1.y - mu) * rs * gv1.y + bv1.y;
    xsm[r][c8 + 6] = (u1.z - mu) * rs * gv1.z + bv1.z;
    xsm[r][c8 + 7] = (u1.w - mu) * rs * gv1.w + bv1.w;
    __syncthreads();

    int cc = t & 127;
    const float* W0 = (t < 128) ? Wq : Wk;
    const float* W1 = (t < 128) ? Wv : Ws;
    float bias0 = ((t < 128) ? bq : bk)[cc];
    float bias1 = ((t < 128) ? bv : bs)[cc];
    float acc0[16], acc1[16];
    #pragma unroll
    for (int i = 0; i < 16; ++i) { acc0[i] = 0.f; acc1[i] = 0.f; }
    for (int k0 = 0; k0 < 128; k0 += 4) {
        float w00 = W0[(k0 + 0) * 128 + cc];
        float w01 = W0[(k0 + 1) * 128 + cc];
        float w02 = W0[(k0 + 2) * 128 + cc];
        float w03 = W0[(k0 + 3) * 128 + cc];
        float w10 = W1[(k0 + 0) * 128 + cc];
        float w11 = W1[(k0 + 1) * 128 + cc];
        float w12 = W1[(k0 + 2) * 128 + cc];
        float w13 = W1[(k0 + 3) * 128 + cc];
        #pragma unroll
        for (int rr = 0; rr < 16; ++rr) {
            float4 xv = *(const float4*)&xsm[rr][k0];
            acc0[rr] += xv.x * w00 + xv.y * w01 + xv.z * w02 + xv.w * w03;
            acc1[rr] += xv.x * w10 + xv.y * w11 + xv.z * w12 + xv.w * w13;
        }
    }
    if (t < 128) {
        #pragma unroll
        for (int rr = 0; rr < 16; ++rr) {
            int n = n0 + rr;
            if (n < N) {
                q[(size_t)n * 128 + cc] = acc0[rr] + bias0;
                vb[(size_t)n * 128 + cc] = __float2bfloat16(acc1[rr] + bias1);
            }
        }
    } else {
        #pragma unroll
        for (int rr = 0; rr < 16; ++rr) {
            int n = n0 + rr;
            if (n < N) {
                kb[(size_t)n * 128 + cc] = __float2bfloat16(acc0[rr] + bias0);
                hs[(size_t)n * 128 + cc] = acc1[rr] + bias1;
            }
        }
    }
}

// -------------------------------------------- per-node attention ----------
// One wave per dst node; lane owns channels 2l, 2l+1 (head = l/16).
// No online max: scores are O(+-2) after LN (exp safe in fp32; the reference's
// max-subtraction cancels exactly in alpha). 4-edge unrolled gather batch
// for 4x memory-level parallelism (gathers are L3-latency-bound).
// xout may alias q (block 2): each wave reads q[n] before writing xout[n].
__global__ __launch_bounds__(256) void attn_kernel(
    const float* q, const unsigned short* __restrict__ kp,
    const unsigned short* __restrict__ vp, const float* __restrict__ hs,
    const int* __restrict__ row_start, const int* __restrict__ col_src,
    const float* __restrict__ xin, float* xout, int N)
{
    int wid = threadIdx.x >> 6, lane = threadIdx.x & 63;
    int n = blockIdx.x * 4 + wid;
    if (n >= N) return;
    int c = lane * 2;
    float2 qv = *(const float2*)&q[(size_t)n * 128 + c];
    float qx = qv.x * INV_SQRT_D, qy = qv.y * INV_SQRT_D;
    int beg = row_start[n], end = row_start[n + 1];
    float den = 0.f, a0 = 0.f, a1 = 0.f;
    int i = beg;
    for (; i + 4 <= end; i += 4) {
        int s0 = col_src[i + 0];
        int s1 = col_src[i + 1];
        int s2 = col_src[i + 2];
        int s3 = col_src[i + 3];
        unsigned kk0 = *(const unsigned*)(kp + (size_t)s0 * 128 + c);
        unsigned kk1 = *(const unsigned*)(kp + (size_t)s1 * 128 + c);
        unsigned kk2 = *(const unsigned*)(kp + (size_t)s2 * 128 + c);
        unsigned kk3 = *(const unsigned*)(kp + (size_t)s3 * 128 + c);
        unsigned vv0 = *(const unsigned*)(vp + (size_t)s0 * 128 + c);
        unsigned vv1 = *(const unsigned*)(vp + (size_t)s1 * 128 + c);
        unsigned vv2 = *(const unsigned*)(vp + (size_t)s2 * 128 + c);
        unsigned vv3 = *(const unsigned*)(vp + (size_t)s3 * 128 + c);
        float p0 = qx * __uint_as_float((kk0 & 0xffffu) << 16) +
                   qy * __uint_as_float(kk0 & 0xffff0000u);
        float p1 = qx * __uint_as_float((kk1 & 0xffffu) << 16) +
                   qy * __uint_as_float(kk1 & 0xffff0000u);
        float p2 = qx * __uint_as_float((kk2 & 0xffffu) << 16) +
                   qy * __uint_as_float(kk2 & 0xffff0000u);
        float p3 = qx * __uint_as_float((kk3 & 0xffffu) << 16) +
                   qy * __uint_as_float(kk3 & 0xffff0000u);
        p0 += __shfl_xor(p0, 1); p1 += __shfl_xor(p1, 1);
        p2 += __shfl_xor(p2, 1); p3 += __shfl_xor(p3, 1);
        p0 += __shfl_xor(p0, 2); p1 += __shfl_xor(p1, 2);
        p2 += __shfl_xor(p2, 2); p3 += __shfl_xor(p3, 2);
        p0 += __shfl_xor(p0, 4); p1 += __shfl_xor(p1, 4);
        p2 += __shfl_xor(p2, 4); p3 += __shfl_xor(p3, 4);
        p0 += __shfl_xor(p0, 8); p1 += __shfl_xor(p1, 8);
        p2 += __shfl_xor(p2, 8); p3 += __shfl_xor(p3, 8);
        float w0 = __expf(p0), w1 = __expf(p1), w2 = __expf(p2), w3 = __expf(p3);
        den += (w0 + w1) + (w2 + w3);
        a0 += w0 * __uint_as_float((vv0 & 0xffffu) << 16)
            + w1 * __uint_as_float((vv1 & 0xffffu) << 16)
            + w2 * __uint_as_float((vv2 & 0xffffu) << 16)
            + w3 * __uint_as_float((vv3 & 0xffffu) << 16);
        a1 += w0 * __uint_as_float(vv0 & 0xffff0000u)
            + w1 * __uint_as_float(vv1 & 0xffff0000u)
            + w2 * __uint_as_float(vv2 & 0xffff0000u)
            + w3 * __uint_as_float(vv3 & 0xffff0000u);
    }
    for (; i < end; ++i) {
        int s = col_src[i];
        unsigned kk = *(const unsigned*)(kp + (size_t)s * 128 + c);
        unsigned vv = *(const unsigned*)(vp + (size_t)s * 128 + c);
        float p = qx * __uint_as_float((kk & 0xffffu) << 16) +
                  qy * __uint_as_float(kk & 0xffff0000u);
        p += __shfl_xor(p, 1);
        p += __shfl_xor(p, 2);
        p += __shfl_xor(p, 4);
        p += __shfl_xor(p, 8);
        float w = __expf(p);
        den += w;
        a0 += w * __uint_as_float((vv & 0xffffu) << 16);
        a1 += w * __uint_as_float(vv & 0xffff0000u);
    }
    float inv = 1.f / (den + 1e-16f);
    float2 hv = *(const float2*)&hs[(size_t)n * 128 + c];
    float o0 = a0 * inv + hv.x;
    float o1 = a1 * inv + hv.y;
    o0 = o0 > 0.f ? o0 : 0.f;
    o1 = o1 > 0.f ? o1 : 0.f;
    float2 xv = *(const float2*)&xin[(size_t)n * 128 + c];
    xv.x += o0;
    xv.y += o1;
    *(float2*)&xout[(size_t)n * 128 + c] = xv;
}

// ------------------------------------------------------------- MLP head ---
__global__ __launch_bounds__(256) void head_kernel(
    const float* __restrict__ x, const float* __restrict__ fw,
    const float* __restrict__ fb, const float* __restrict__ ow,
    const float* __restrict__ ob, float* __restrict__ out, int OUTD, int N)
{
    int wid = threadIdx.x >> 6, lane = threadIdx.x & 63;
    int n0 = (blockIdx.x * 4 + wid) * 4;
    if (n0 >= N) return;
    float2 xr[4];
    #pragma unroll
    for (int j = 0; j < 4; ++j) {
        int n = n0 + j;
        xr[j] = (n < N) ? *(const float2*)&x[(size_t)n * 128 + lane * 2]
                        : make_float2(0.f, 0.f);
    }
    float acc[4][2];
    #pragma unroll
    for (int j = 0; j < 4; ++j) { acc[j][0] = 0.f; acc[j][1] = 0.f; }
    for (int k = 0; k < 128; ++k) {
        float w0 = fw[k * 128 + lane];
        float w1 = fw[k * 128 + 64 + lane];
        int srcl = k >> 1;
        #pragma unroll
        for (int j = 0; j < 4; ++j) {
            float xk = __shfl((k & 1) ? xr[j].y : xr[j].x, srcl);
            acc[j][0] += xk * w0;
            acc[j][1] += xk * w1;
        }
    }
    float b0 = fb[lane], b1 = fb[64 + lane];
    #pragma unroll
    for (int j = 0; j < 4; ++j) {
        int n = n0 + j;
        if (n >= N) break;  // wave-uniform
        float t0 = acc[j][0] + b0; t0 = (t0 > 0.f) ? t0 : 0.2f * t0;
        float t1 = acc[j][1] + b1; t1 = (t1 > 0.f) ? t1 : 0.2f * t1;
        for (int jo = 0; jo < OUTD; ++jo) {
            float p = t0 * ow[lane * OUTD + jo] + t1 * ow[(64 + lane) * OUTD + jo];
            p += __shfl_xor(p, 32);
            p += __shfl_xor(p, 16);
            p += __shfl_xor(p, 8);
            p += __shfl_xor(p, 4);
            p += __shfl_xor(p, 2);
            p += __shfl_xor(p, 1);
            if (lane == 0) out[(size_t)n * OUTD + jo] = p + ob[jo];
        }
    }
}

// ------------------------------------------------------------------ host --
static inline size_t align_up(size_t v, size_t a) { return (v + a - 1) & ~(a - 1); }

extern "C" void kernel_launch(void* const* d_in, const int* in_sizes, int n_in,
                              void* d_out, int out_size, void* d_ws, size_t ws_size,
                              hipStream_t stream)
{
    const float* xs = (const float*)d_in[0];
    const float* xd = (const float*)d_in[1];
    const float* xp = (const float*)d_in[2];
    const float* xt = (const float*)d_in[3];
    const int* edge = (const int*)d_in[4];
    const float* proj_w = (const float*)d_in[5];
    const float* ln_g = (const float*)d_in[6];
    const float* ln_b = (const float*)d_in[7];
    const float* Wq = (const float*)d_in[8];
    const float* bq = (const float*)d_in[9];
    const float* Wk = (const float*)d_in[10];
    const float* bk = (const float*)d_in[11];
    const float* Wv = (const float*)d_in[12];
    const float* bv = (const float*)d_in[13];
    const float* Ws = (const float*)d_in[14];
    const float* bs = (const float*)d_in[15];
    const float* fc1_w = (const float*)d_in[16];
    const float* fc1_b = (const float*)d_in[17];
    const float* fc2_w = (const float*)d_in[18];
    const float* fc2_b = (const float*)d_in[19];
    const float* fc3_w = (const float*)d_in[20];
    const float* fc3_b = (const float*)d_in[21];
    const float* fc4_w = (const float*)d_in[22];
    const float* fc4_b = (const float*)d_in[23];

    int N = in_sizes[0] / 22;
    int E = in_sizes[4] / 2;
    const int* srcp = edge;
    const int* dstp = edge + E;

    // workspace carve-up
    char* w = (char*)d_ws;
    size_t off = 0;
    auto take = [&](size_t bytes) {
        char* p = w + off;
        off = align_up(off + bytes, 256);
        return p;
    };
    float* x = (float*)take((size_t)N * 128 * 4);
    float* q = (float*)take((size_t)N * 128 * 4);
    float* hsb = (float*)take((size_t)N * 128 * 4);
    __hip_bfloat16* kb = (__hip_bfloat16*)take((size_t)N * 128 * 2);
    __hip_bfloat16* vb = (__hip_bfloat16*)take((size_t)N * 128 * 2);
    int* deg = (int*)take((size_t)N * 4);
    int* row_start = (int*)take((size_t)(N + 1) * 4);
    int* cursor = (int*)take((size_t)N * 4);
    int* col_src = (int*)take((size_t)E * 4);
    if (off > ws_size) {
        fprintf(stderr, "kernel_launch: ws too small (%zu > %zu)\n", off, ws_size);
        return;
    }

    float* out = (float*)d_out;

    // CSR build
    hipMemsetAsync(deg, 0, (size_t)N * 4, stream);
    deg_kernel<<<(E + 255) / 256, 256, 0, stream>>>(dstp, deg, E);
    scan_kernel<<<1, 1024, 0, stream>>>(deg, row_start, cursor, N);
    scatter_kernel<<<(E + 255) / 256, 256, 0, stream>>>(srcp, dstp, cursor, col_src, E);

    // input projection
    proj_kernel<<<((size_t)N * 128 + 255) / 256, 256, 0, stream>>>(
        xs, xd, xp, xt, proj_w, x, N);

    int gemm_blocks = (N + 15) / 16;
    int attn_blocks = (N + 3) / 4;
    int head_blocks = (N + 15) / 16;

    const unsigned short* kpu = (const unsigned short*)kb;
    const unsigned short* vpu = (const unsigned short*)vb;

    // block 0: x = blk(x, 0)
    lngemm_kernel<<<gemm_blocks, 256, 0, stream>>>(
        x, ln_g + 0 * 128, ln_b + 0 * 128,
        Wq + (size_t)0 * 16384, bq + 0 * 128, Wk + (size_t)0 * 16384, bk + 0 * 128,
        Wv + (size_t)0 * 16384, bv + 0 * 128, Ws + (size_t)0 * 16384, bs + 0 * 128,
        q, kb, vb, hsb, N);
    attn_kernel<<<attn_blocks, 256, 0, stream>>>(
        q, kpu, vpu, hsb, row_start, col_src, x, x, N);

    // block 1: x = blk(x, 1)
    lngemm_kernel<<<gemm_blocks, 256, 0, stream>>>(
        x, ln_g + 1 * 128, ln_b + 1 * 128,
        Wq + (size_t)1 * 16384, bq + 1 * 128, Wk + (size_t)1 * 16384, bk + 1 * 128,
        Wv + (size_t)1 * 16384, bv + 1 * 128, Ws + (size_t)1 * 16384, bs + 1 * 128,
        q, kb, vb, hsb, N);
    attn_kernel<<<attn_blocks, 256, 0, stream>>>(
        q, kpu, vpu, hsb, row_start, col_src, x, x, N);

    // block 2: x_pi = blk(x, 2) -> result into q buffer (x stays intact)
    lngemm_kernel<<<gemm_blocks, 256, 0, stream>>>(
        x, ln_g + 2 * 128, ln_b + 2 * 128,
        Wq + (size_t)2 * 16384, bq + 2 * 128, Wk + (size_t)2 * 16384, bk + 2 * 128,
        Wv + (size_t)2 * 16384, bv + 2 * 128, Ws + (size_t)2 * 16384, bs + 2 * 128,
        q, kb, vb, hsb, N);
    attn_kernel<<<attn_blocks, 256, 0, stream>>>(
        q, kpu, vpu, hsb, row_start, col_src, x, q, N);  // xout = q = x_pi

    // prog head from x_pi (q buffer) -- must precede block 3 (overwrites q)
    head_kernel<<<head_blocks, 256, 0, stream>>>(
        q, fc1_w, fc1_b, fc3_w, fc3_b, out, 7, N);

    // block 3: x_dg = blk(x, 3) -- branches off the SAME post-block-1 x
    lngemm_kernel<<<gemm_blocks, 256, 0, stream>>>(
        x, ln_g + 3 * 128, ln_b + 3 * 128,
        Wq + (size_t)3 * 16384, bq + 3 * 128, Wk + (size_t)3 * 16384, bk + 3 * 128,
        Wv + (size_t)3 * 16384, bv + 3 * 128, Ws + (size_t)3 * 16384, bs + 3 * 128,
        q, kb, vb, hsb, N);
    attn_kernel<<<attn_blocks, 256, 0, stream>>>(
        q, kpu, vpu, hsb, row_start, col_src, x, x, N);

    // diag head from x_dg (x buffer)
    head_kernel<<<head_blocks, 256, 0, stream>>>(
        x, fc2_w, fc2_b, fc4_w, fc4_b, out + (size_t)N * 7, 3, N);
}

// Round 7
// 1873.036 us; speedup vs baseline: 1.2232x; 1.0923x over previous
//
#include <hip/hip_runtime.h>
#include <hip/hip_bf16.h>
#include <cstdio>

#define INV_SQRT_D 0.17677669529663687f

typedef __attribute__((ext_vector_type(8))) short short8;
typedef __attribute__((ext_vector_type(4))) float f32x4;

static __device__ __forceinline__ unsigned short f2bf(float f) {
    __hip_bfloat16 h = __float2bfloat16(f);
    return *reinterpret_cast<unsigned short*>(&h);
}

// ---------------------------------------------------------------- proj ----
__global__ __launch_bounds__(256) void proj_kernel(
    const float* __restrict__ xs, const float* __restrict__ xd,
    const float* __restrict__ xp, const float* __restrict__ xt,
    const float* __restrict__ W, float* __restrict__ x, int N)
{
    int idx = blockIdx.x * 256 + threadIdx.x;
    if (idx >= N * 128) return;
    int n = idx >> 7, c = idx & 127;
    const float* w = W + c;
    float acc = 0.f;
    const float* a = xs + (size_t)n * 22;
    #pragma unroll
    for (int k = 0; k < 22; ++k) acc += a[k] * w[(k) * 128];
    const float* b = xd + (size_t)n * 12;
    #pragma unroll
    for (int k = 0; k < 12; ++k) acc += b[k] * w[(22 + k) * 128];
    const float* p = xp + (size_t)n * 7;
    #pragma unroll
    for (int k = 0; k < 7; ++k) acc += p[k] * w[(34 + k) * 128];
    const float* t = xt + (size_t)n * 4;
    #pragma unroll
    for (int k = 0; k < 4; ++k) acc += t[k] * w[(41 + k) * 128];
    x[idx] = acc;
}

// ----------------------------------------------------------- CSR build ----
__global__ __launch_bounds__(256) void deg_kernel(
    const int* __restrict__ dst, int* __restrict__ deg, int E)
{
    int e = blockIdx.x * 256 + threadIdx.x;
    if (e < E) atomicAdd(&deg[dst[e]], 1);
}

__global__ __launch_bounds__(1024) void scan_kernel(
    const int* __restrict__ deg, int* __restrict__ row_start,
    int* __restrict__ cursor, int n)
{
    __shared__ int buf[2][1024];
    int t = threadIdx.x;
    int per = (n + 1023) >> 10;
    int start = t * per;
    int s = 0;
    for (int j = 0; j < per; ++j) {
        int idx = start + j;
        if (idx < n) s += deg[idx];
    }
    int x = s;
    buf[0][t] = x;
    __syncthreads();
    int sel = 0;
    for (int off = 1; off < 1024; off <<= 1) {
        int y = (t >= off) ? buf[sel][t - off] : 0;
        x += y;
        buf[sel ^ 1][t] = x;
        sel ^= 1;
        __syncthreads();
    }
    int run = x - s;  // exclusive prefix base
    for (int j = 0; j < per; ++j) {
        int idx = start + j;
        if (idx < n) {
            row_start[idx] = run;
            cursor[idx] = run;
            run += deg[idx];
        }
    }
    if (t == 1023) row_start[n] = x;
}

__global__ __launch_bounds__(256) void scatter_kernel(
    const int* __restrict__ src, const int* __restrict__ dst,
    int* __restrict__ cursor, int* __restrict__ col_src, int E)
{
    int e = blockIdx.x * 256 + threadIdx.x;
    if (e < E) {
        int d = dst[e];
        int pos = atomicAdd(&cursor[d], 1);
        col_src[pos] = src[e];
    }
}

// ------------------------------------------- weight convert + transpose ---
// Whi[(layer*4+which)*128 + c][k] = bf16(W[k][c]). 256 blocks: 16 mats x 16 tiles.
__global__ __launch_bounds__(256) void wcvt_kernel(
    const float* __restrict__ Wq, const float* __restrict__ Wk,
    const float* __restrict__ Wv, const float* __restrict__ Ws,
    unsigned short* __restrict__ Whi)
{
    __shared__ float lds[32][33];
    int b = blockIdx.x;
    int mat = b >> 4;          // 0..15
    int layer = mat >> 2, which = mat & 3;
    int tr = (b >> 2) & 3, tc = b & 3;
    int k0 = tr * 32, c0 = tc * 32;
    const float* Wsrc =
        (which == 0 ? Wq : which == 1 ? Wk : which == 2 ? Wv : Ws) +
        (size_t)layer * 16384;
    int t = threadIdx.x;
    #pragma unroll
    for (int i = 0; i < 4; ++i) {
        int kk = (t >> 5) + 8 * i, cc = t & 31;
        lds[kk][cc] = Wsrc[(size_t)(k0 + kk) * 128 + c0 + cc];
    }
    __syncthreads();
    #pragma unroll
    for (int i = 0; i < 4; ++i) {
        int cc = (t >> 5) + 8 * i, kk = t & 31;
        Whi[((size_t)mat * 128 + c0 + cc) * 128 + k0 + kk] = f2bf(lds[kk][cc]);
    }
}

// ---------------------------------- fp32 LN + single GEMM: hs = ln(x)@Ws+bs
// 32 rows/block, 256 thr; thread owns 8 rows x 2 cols (better LDS:FMA ratio).
// hs is the error-critical output (directly additive into residual stream),
// so it stays on the exact fp32 path.
__global__ __launch_bounds__(256) void lngemm_hs(
    const float* __restrict__ x, const float* __restrict__ g, const float* __restrict__ bb,
    const float* __restrict__ Ws, const float* __restrict__ bs,
    float* __restrict__ hs, int N)
{
    __shared__ float xsm[32][132];
    int t = threadIdx.x;
    int n0 = blockIdx.x * 32;
    {
        int r = t >> 3, cg = t & 7;          // 8 threads per row, 16 cols each
        int row = n0 + r;
        int rowc = row < N ? row : N - 1;
        const float* xr = x + (size_t)rowc * 128 + cg * 16;
        float4 u[4];
        #pragma unroll
        for (int i = 0; i < 4; ++i) u[i] = *(const float4*)(xr + i * 4);
        float s = 0.f, ss = 0.f;
        #pragma unroll
        for (int i = 0; i < 4; ++i) {
            s += u[i].x + u[i].y + u[i].z + u[i].w;
            ss += u[i].x * u[i].x + u[i].y * u[i].y + u[i].z * u[i].z + u[i].w * u[i].w;
        }
        s += __shfl_xor(s, 1); ss += __shfl_xor(ss, 1);
        s += __shfl_xor(s, 2); ss += __shfl_xor(ss, 2);
        s += __shfl_xor(s, 4); ss += __shfl_xor(ss, 4);
        float mu = s * (1.f / 128.f);
        float var = ss * (1.f / 128.f) - mu * mu;
        float rsv = rsqrtf(var + 1e-5f);
        const float* gp = g + cg * 16;
        const float* bp = bb + cg * 16;
        #pragma unroll
        for (int i = 0; i < 4; ++i) {
            float4 gv = *(const float4*)(gp + i * 4);
            float4 bv = *(const float4*)(bp + i * 4);
            float4 y;
            y.x = (u[i].x - mu) * rsv * gv.x + bv.x;
            y.y = (u[i].y - mu) * rsv * gv.y + bv.y;
            y.z = (u[i].z - mu) * rsv * gv.z + bv.z;
            y.w = (u[i].w - mu) * rsv * gv.w + bv.w;
            *(float4*)&xsm[r][cg * 16 + i * 4] = y;
        }
    }
    __syncthreads();

    int rg = t >> 6;           // 0..3 -> rows rg*8..rg*8+7
    int c0 = (t & 63) * 2;     // 2 cols
    float acc0[8], acc1[8];
    #pragma unroll
    for (int i = 0; i < 8; ++i) { acc0[i] = 0.f; acc1[i] = 0.f; }
    for (int k = 0; k < 128; k += 4) {
        float2 w0 = *(const float2*)(Ws + (size_t)(k + 0) * 128 + c0);
        float2 w1 = *(const float2*)(Ws + (size_t)(k + 1) * 128 + c0);
        float2 w2 = *(const float2*)(Ws + (size_t)(k + 2) * 128 + c0);
        float2 w3 = *(const float2*)(Ws + (size_t)(k + 3) * 128 + c0);
        #pragma unroll
        for (int rr = 0; rr < 8; ++rr) {
            float4 xv = *(const float4*)&xsm[rg * 8 + rr][k];
            acc0[rr] += xv.x * w0.x + xv.y * w1.x + xv.z * w2.x + xv.w * w3.x;
            acc1[rr] += xv.x * w0.y + xv.y * w1.y + xv.z * w2.y + xv.w * w3.y;
        }
    }
    float b0 = bs[c0], b1 = bs[c0 + 1];
    #pragma unroll
    for (int rr = 0; rr < 8; ++rr) {
        int row = n0 + rg * 8 + rr;
        if (row < N) {
            float2 o = make_float2(acc0[rr] + b0, acc1[rr] + b1);
            *(float2*)&hs[(size_t)row * 128 + c0] = o;
        }
    }
}

// ----------------------- plain-bf16 reg-direct MFMA: q (f32), k, v (bf16) --
// 16 rows/block, 192 thr = 3 waves; wave w -> mat w (0:q, 1:k, 2:v).
// q,k,v errors are softmax-suppressed (scores/alpha-averaged), so plain bf16
// MFMA noise (~1e-3, comparable to k/v's existing bf16-storage rounding) is safe.
__global__ __launch_bounds__(192) void qkv_mfma(
    const float* __restrict__ x, const float* __restrict__ g, const float* __restrict__ bb,
    const unsigned short* __restrict__ Wth,   // layer slab: 4 mats x [128 cols][128 k]
    const float* __restrict__ bq, const float* __restrict__ bk, const float* __restrict__ bv,
    float* __restrict__ q, __hip_bfloat16* __restrict__ kbo,
    __hip_bfloat16* __restrict__ vbo, int N)
{
    __shared__ float lmu[16], lrs[16];
    int t = threadIdx.x;
    int n0 = blockIdx.x * 16;

    if (t < 128) {   // LN stats: 8 threads per row
        int r = t >> 3, cg = t & 7;
        int row = n0 + r;
        int rowc = row < N ? row : N - 1;
        const float* xr = x + (size_t)rowc * 128 + cg * 16;
        float s = 0.f, ss = 0.f;
        #pragma unroll
        for (int i = 0; i < 4; ++i) {
            float4 u = *(const float4*)(xr + i * 4);
            s += u.x + u.y + u.z + u.w;
            ss += u.x * u.x + u.y * u.y + u.z * u.z + u.w * u.w;
        }
        s += __shfl_xor(s, 1); ss += __shfl_xor(ss, 1);
        s += __shfl_xor(s, 2); ss += __shfl_xor(ss, 2);
        s += __shfl_xor(s, 4); ss += __shfl_xor(ss, 4);
        float mu = s * (1.f / 128.f);
        float var = ss * (1.f / 128.f) - mu * mu;
        float rsv = rsqrtf(var + 1e-5f);
        if (cg == 0) { lmu[r] = mu; lrs[r] = rsv; }
    }
    __syncthreads();

    int w = t >> 6;            // 0:q, 1:k, 2:v
    int l = t & 63;
    int lr = l & 15, lk = l >> 4;
    const unsigned short* Wh = Wth + (size_t)w * 16384;  // mat slab w
    int arow = n0 + lr;
    int arowc = arow < N ? arow : (N - 1);
    float mu = lmu[lr], rsv = lrs[lr];

    f32x4 acc[8];
    #pragma unroll
    for (int n = 0; n < 8; ++n) acc[n] = (f32x4){0.f, 0.f, 0.f, 0.f};

    #pragma unroll
    for (int ks = 0; ks < 4; ++ks) {
        int k0 = ks * 32 + lk * 8;
        const float* xp = x + (size_t)arowc * 128 + k0;
        short8 ah;
        #pragma unroll
        for (int jj = 0; jj < 2; ++jj) {
            float4 xv = *(const float4*)(xp + jj * 4);
            float4 gv = *(const float4*)(g + k0 + jj * 4);
            float4 bv = *(const float4*)(bb + k0 + jj * 4);
            ah[jj * 4 + 0] = (short)f2bf((xv.x - mu) * rsv * gv.x + bv.x);
            ah[jj * 4 + 1] = (short)f2bf((xv.y - mu) * rsv * gv.y + bv.y);
            ah[jj * 4 + 2] = (short)f2bf((xv.z - mu) * rsv * gv.z + bv.z);
            ah[jj * 4 + 3] = (short)f2bf((xv.w - mu) * rsv * gv.w + bv.w);
        }
        #pragma unroll
        for (int n = 0; n < 8; ++n) {
            short8 bh = *(const short8*)(Wh + (size_t)(n * 16 + lr) * 128 + k0);
            acc[n] = __builtin_amdgcn_mfma_f32_16x16x32_bf16(ah, bh, acc[n], 0, 0, 0);
        }
    }

    const float* bias = (w == 0) ? bq : (w == 1) ? bk : bv;
    #pragma unroll
    for (int n = 0; n < 8; ++n) {
        int col = n * 16 + lr;
        float bsv = bias[col];
        #pragma unroll
        for (int j = 0; j < 4; ++j) {
            int orow = n0 + lk * 4 + j;
            if (orow < N) {
                float v = acc[n][j] + bsv;
                size_t o = (size_t)orow * 128 + col;
                if (w == 0) q[o] = v;
                else if (w == 1) kbo[o] = __float2bfloat16(v);
                else vbo[o] = __float2bfloat16(v);
            }
        }
    }
}

// -------------------------------------------- per-node attention ----------
// (round-5 proven) One wave per dst node; lane owns channels 2l, 2l+1.
// No online max (scores O(+-2) after LN; max-subtraction cancels in alpha).
// 4-edge unrolled gather batch for memory-level parallelism.
// xout may alias q (block 2): each wave reads q[n] before writing xout[n].
__global__ __launch_bounds__(256) void attn_kernel(
    const float* q, const unsigned short* __restrict__ kp,
    const unsigned short* __restrict__ vp, const float* __restrict__ hs,
    const int* __restrict__ row_start, const int* __restrict__ col_src,
    const float* __restrict__ xin, float* xout, int N)
{
    int wid = threadIdx.x >> 6, lane = threadIdx.x & 63;
    int n = blockIdx.x * 4 + wid;
    if (n >= N) return;
    int c = lane * 2;
    float2 qv = *(const float2*)&q[(size_t)n * 128 + c];
    float qx = qv.x * INV_SQRT_D, qy = qv.y * INV_SQRT_D;
    int beg = row_start[n], end = row_start[n + 1];
    float den = 0.f, a0 = 0.f, a1 = 0.f;
    int i = beg;
    for (; i + 4 <= end; i += 4) {
        int s0 = col_src[i + 0];
        int s1 = col_src[i + 1];
        int s2 = col_src[i + 2];
        int s3 = col_src[i + 3];
        unsigned kk0 = *(const unsigned*)(kp + (size_t)s0 * 128 + c);
        unsigned kk1 = *(const unsigned*)(kp + (size_t)s1 * 128 + c);
        unsigned kk2 = *(const unsigned*)(kp + (size_t)s2 * 128 + c);
        unsigned kk3 = *(const unsigned*)(kp + (size_t)s3 * 128 + c);
        unsigned vv0 = *(const unsigned*)(vp + (size_t)s0 * 128 + c);
        unsigned vv1 = *(const unsigned*)(vp + (size_t)s1 * 128 + c);
        unsigned vv2 = *(const unsigned*)(vp + (size_t)s2 * 128 + c);
        unsigned vv3 = *(const unsigned*)(vp + (size_t)s3 * 128 + c);
        float p0 = qx * __uint_as_float((kk0 & 0xffffu) << 16) +
                   qy * __uint_as_float(kk0 & 0xffff0000u);
        float p1 = qx * __uint_as_float((kk1 & 0xffffu) << 16) +
                   qy * __uint_as_float(kk1 & 0xffff0000u);
        float p2 = qx * __uint_as_float((kk2 & 0xffffu) << 16) +
                   qy * __uint_as_float(kk2 & 0xffff0000u);
        float p3 = qx * __uint_as_float((kk3 & 0xffffu) << 16) +
                   qy * __uint_as_float(kk3 & 0xffff0000u);
        p0 += __shfl_xor(p0, 1); p1 += __shfl_xor(p1, 1);
        p2 += __shfl_xor(p2, 1); p3 += __shfl_xor(p3, 1);
        p0 += __shfl_xor(p0, 2); p1 += __shfl_xor(p1, 2);
        p2 += __shfl_xor(p2, 2); p3 += __shfl_xor(p3, 2);
        p0 += __shfl_xor(p0, 4); p1 += __shfl_xor(p1, 4);
        p2 += __shfl_xor(p2, 4); p3 += __shfl_xor(p3, 4);
        p0 += __shfl_xor(p0, 8); p1 += __shfl_xor(p1, 8);
        p2 += __shfl_xor(p2, 8); p3 += __shfl_xor(p3, 8);
        float w0 = __expf(p0), w1 = __expf(p1), w2 = __expf(p2), w3 = __expf(p3);
        den += (w0 + w1) + (w2 + w3);
        a0 += w0 * __uint_as_float((vv0 & 0xffffu) << 16)
            + w1 * __uint_as_float((vv1 & 0xffffu) << 16)
            + w2 * __uint_as_float((vv2 & 0xffffu) << 16)
            + w3 * __uint_as_float((vv3 & 0xffffu) << 16);
        a1 += w0 * __uint_as_float(vv0 & 0xffff0000u)
            + w1 * __uint_as_float(vv1 & 0xffff0000u)
            + w2 * __uint_as_float(vv2 & 0xffff0000u)
            + w3 * __uint_as_float(vv3 & 0xffff0000u);
    }
    for (; i < end; ++i) {
        int s = col_src[i];
        unsigned kk = *(const unsigned*)(kp + (size_t)s * 128 + c);
        unsigned vv = *(const unsigned*)(vp + (size_t)s * 128 + c);
        float p = qx * __uint_as_float((kk & 0xffffu) << 16) +
                  qy * __uint_as_float(kk & 0xffff0000u);
        p += __shfl_xor(p, 1);
        p += __shfl_xor(p, 2);
        p += __shfl_xor(p, 4);
        p += __shfl_xor(p, 8);
        float w = __expf(p);
        den += w;
        a0 += w * __uint_as_float((vv & 0xffffu) << 16);
        a1 += w * __uint_as_float(vv & 0xffff0000u);
    }
    float inv = 1.f / (den + 1e-16f);
    float2 hv = *(const float2*)&hs[(size_t)n * 128 + c];
    float o0 = a0 * inv + hv.x;
    float o1 = a1 * inv + hv.y;
    o0 = o0 > 0.f ? o0 : 0.f;
    o1 = o1 > 0.f ? o1 : 0.f;
    float2 xv = *(const float2*)&xin[(size_t)n * 128 + c];
    xv.x += o0;
    xv.y += o1;
    *(float2*)&xout[(size_t)n * 128 + c] = xv;
}

// ------------------------------------------------------------- MLP head ---
__global__ __launch_bounds__(256) void head_kernel(
    const float* __restrict__ x, const float* __restrict__ fw,
    const float* __restrict__ fb, const float* __restrict__ ow,
    const float* __restrict__ ob, float* __restrict__ out, int OUTD, int N)
{
    int wid = threadIdx.x >> 6, lane = threadIdx.x & 63;
    int n0 = (blockIdx.x * 4 + wid) * 4;
    if (n0 >= N) return;
    float2 xr[4];
    #pragma unroll
    for (int j = 0; j < 4; ++j) {
        int n = n0 + j;
        xr[j] = (n < N) ? *(const float2*)&x[(size_t)n * 128 + lane * 2]
                        : make_float2(0.f, 0.f);
    }
    float acc[4][2];
    #pragma unroll
    for (int j = 0; j < 4; ++j) { acc[j][0] = 0.f; acc[j][1] = 0.f; }
    for (int k = 0; k < 128; ++k) {
        float w0 = fw[k * 128 + lane];
        float w1 = fw[k * 128 + 64 + lane];
        int srcl = k >> 1;
        #pragma unroll
        for (int j = 0; j < 4; ++j) {
            float xk = __shfl((k & 1) ? xr[j].y : xr[j].x, srcl);
            acc[j][0] += xk * w0;
            acc[j][1] += xk * w1;
        }
    }
    float b0 = fb[lane], b1 = fb[64 + lane];
    #pragma unroll
    for (int j = 0; j < 4; ++j) {
        int n = n0 + j;
        if (n >= N) break;  // wave-uniform
        float t0 = acc[j][0] + b0; t0 = (t0 > 0.f) ? t0 : 0.2f * t0;
        float t1 = acc[j][1] + b1; t1 = (t1 > 0.f) ? t1 : 0.2f * t1;
        for (int jo = 0; jo < OUTD; ++jo) {
            float p = t0 * ow[lane * OUTD + jo] + t1 * ow[(64 + lane) * OUTD + jo];
            p += __shfl_xor(p, 32);
            p += __shfl_xor(p, 16);
            p += __shfl_xor(p, 8);
            p += __shfl_xor(p, 4);
            p += __shfl_xor(p, 2);
            p += __shfl_xor(p, 1);
            if (lane == 0) out[(size_t)n * OUTD + jo] = p + ob[jo];
        }
    }
}

// ------------------------------------------------------------------ host --
static inline size_t align_up(size_t v, size_t a) { return (v + a - 1) & ~(a - 1); }

extern "C" void kernel_launch(void* const* d_in, const int* in_sizes, int n_in,
                              void* d_out, int out_size, void* d_ws, size_t ws_size,
                              hipStream_t stream)
{
    const float* xs = (const float*)d_in[0];
    const float* xd = (const float*)d_in[1];
    const float* xp = (const float*)d_in[2];
    const float* xt = (const float*)d_in[3];
    const int* edge = (const int*)d_in[4];
    const float* proj_w = (const float*)d_in[5];
    const float* ln_g = (const float*)d_in[6];
    const float* ln_b = (const float*)d_in[7];
    const float* Wq = (const float*)d_in[8];
    const float* bq = (const float*)d_in[9];
    const float* Wk = (const float*)d_in[10];
    const float* bk = (const float*)d_in[11];
    const float* Wv = (const float*)d_in[12];
    const float* bv = (const float*)d_in[13];
    const float* Ws = (const float*)d_in[14];
    const float* bs = (const float*)d_in[15];
    const float* fc1_w = (const float*)d_in[16];
    const float* fc1_b = (const float*)d_in[17];
    const float* fc2_w = (const float*)d_in[18];
    const float* fc2_b = (const float*)d_in[19];
    const float* fc3_w = (const float*)d_in[20];
    const float* fc3_b = (const float*)d_in[21];
    const float* fc4_w = (const float*)d_in[22];
    const float* fc4_b = (const float*)d_in[23];

    int N = in_sizes[0] / 22;
    int E = in_sizes[4] / 2;
    const int* srcp = edge;
    const int* dstp = edge + E;

    // workspace carve-up
    char* w = (char*)d_ws;
    size_t off = 0;
    auto take = [&](size_t bytes) {
        char* p = w + off;
        off = align_up(off + bytes, 256);
        return p;
    };
    float* x = (float*)take((size_t)N * 128 * 4);
    float* q = (float*)take((size_t)N * 128 * 4);
    float* hsb = (float*)take((size_t)N * 128 * 4);
    __hip_bfloat16* kb = (__hip_bfloat16*)take((size_t)N * 128 * 2);
    __hip_bfloat16* vb = (__hip_bfloat16*)take((size_t)N * 128 * 2);
    unsigned short* wth = (unsigned short*)take((size_t)16 * 128 * 128 * 2);
    int* deg = (int*)take((size_t)N * 4);
    int* row_start = (int*)take((size_t)(N + 1) * 4);
    int* cursor = (int*)take((size_t)N * 4);
    int* col_src = (int*)take((size_t)E * 4);
    if (off > ws_size) {
        fprintf(stderr, "kernel_launch: ws too small (%zu > %zu)\n", off, ws_size);
        return;
    }

    float* out = (float*)d_out;

    // weight convert+transpose (bf16 [col][k], all 4 layers)
    wcvt_kernel<<<256, 256, 0, stream>>>(Wq, Wk, Wv, Ws, wth);

    // CSR build
    hipMemsetAsync(deg, 0, (size_t)N * 4, stream);
    deg_kernel<<<(E + 255) / 256, 256, 0, stream>>>(dstp, deg, E);
    scan_kernel<<<1, 1024, 0, stream>>>(deg, row_start, cursor, N);
    scatter_kernel<<<(E + 255) / 256, 256, 0, stream>>>(srcp, dstp, cursor, col_src, E);

    // input projection
    proj_kernel<<<((size_t)N * 128 + 255) / 256, 256, 0, stream>>>(
        xs, xd, xp, xt, proj_w, x, N);

    int hs_blocks = (N + 31) / 32;
    int qkv_blocks = (N + 15) / 16;
    int attn_blocks = (N + 3) / 4;
    int head_blocks = (N + 15) / 16;

    const unsigned short* kpu = (const unsigned short*)kb;
    const unsigned short* vpu = (const unsigned short*)vb;

    for (int l = 0; l < 4; ++l) {
        qkv_mfma<<<qkv_blocks, 192, 0, stream>>>(
            x, ln_g + l * 128, ln_b + l * 128, wth + (size_t)l * 65536,
            bq + l * 128, bk + l * 128, bv + l * 128, q, kb, vb, N);
        lngemm_hs<<<hs_blocks, 256, 0, stream>>>(
            x, ln_g + l * 128, ln_b + l * 128,
            Ws + (size_t)l * 16384, bs + l * 128, hsb, N);
        if (l == 2) {
            // block 2: x_pi -> q buffer (x stays intact for block 3)
            attn_kernel<<<attn_blocks, 256, 0, stream>>>(
                q, kpu, vpu, hsb, row_start, col_src, x, q, N);
            head_kernel<<<head_blocks, 256, 0, stream>>>(
                q, fc1_w, fc1_b, fc3_w, fc3_b, out, 7, N);
        } else {
            attn_kernel<<<attn_blocks, 256, 0, stream>>>(
                q, kpu, vpu, hsb, row_start, col_src, x, x, N);
        }
    }

    // diag head from x_dg (x buffer)
    head_kernel<<<head_blocks, 256, 0, stream>>>(
        x, fc2_w, fc2_b, fc4_w, fc4_b, out + (size_t)N * 7, 3, N);
}

// Round 8
// 1681.151 us; speedup vs baseline: 1.3628x; 1.1141x over previous
//
#include <hip/hip_runtime.h>
#include <hip/hip_bf16.h>
#include <cstdio>

#define INV_SQRT_D 0.17677669529663687f

typedef __attribute__((ext_vector_type(8))) short short8;
typedef __attribute__((ext_vector_type(4))) float f32x4;

static __device__ __forceinline__ unsigned short f2bf(float f) {
    __hip_bfloat16 h = __float2bfloat16(f);
    return *reinterpret_cast<unsigned short*>(&h);
}
static __device__ __forceinline__ float bf2f(unsigned short u) {
    return __uint_as_float(((unsigned)u) << 16);
}

// ---------------------------------------------------------------- proj ----
__global__ __launch_bounds__(256) void proj_kernel(
    const float* __restrict__ xs, const float* __restrict__ xd,
    const float* __restrict__ xp, const float* __restrict__ xt,
    const float* __restrict__ W, float* __restrict__ x, int N)
{
    int idx = blockIdx.x * 256 + threadIdx.x;
    if (idx >= N * 128) return;
    int n = idx >> 7, c = idx & 127;
    const float* w = W + c;
    float acc = 0.f;
    const float* a = xs + (size_t)n * 22;
    #pragma unroll
    for (int k = 0; k < 22; ++k) acc += a[k] * w[(k) * 128];
    const float* b = xd + (size_t)n * 12;
    #pragma unroll
    for (int k = 0; k < 12; ++k) acc += b[k] * w[(22 + k) * 128];
    const float* p = xp + (size_t)n * 7;
    #pragma unroll
    for (int k = 0; k < 7; ++k) acc += p[k] * w[(34 + k) * 128];
    const float* t = xt + (size_t)n * 4;
    #pragma unroll
    for (int k = 0; k < 4; ++k) acc += t[k] * w[(41 + k) * 128];
    x[idx] = acc;
}

// ----------------------------------------------------------- CSR build ----
__global__ __launch_bounds__(256) void deg_kernel(
    const int* __restrict__ dst, int* __restrict__ deg, int E)
{
    int e = blockIdx.x * 256 + threadIdx.x;
    if (e < E) atomicAdd(&deg[dst[e]], 1);
}

// Parallel scan, 3 kernels (replaces 208us single-block scan).
// A: per-1024-chunk sums (int4-coalesced).
__global__ __launch_bounds__(256) void scan_reduce(
    const int* __restrict__ deg, int* __restrict__ blocksum, int n)
{
    int b = blockIdx.x, t = threadIdx.x;
    int idx = b * 1024 + t * 4;
    int s = 0;
    if (idx + 3 < n) {
        int4 v = *(const int4*)(deg + idx);
        s = v.x + v.y + v.z + v.w;
    } else if (idx < n) {
        s = deg[idx];
        if (idx + 1 < n) s += deg[idx + 1];
        if (idx + 2 < n) s += deg[idx + 2];
        if (idx + 3 < n) s += deg[idx + 3];
    }
    #pragma unroll
    for (int off = 1; off < 64; off <<= 1) s += __shfl_xor(s, off);
    __shared__ int ws[4];
    if ((t & 63) == 0) ws[t >> 6] = s;
    __syncthreads();
    if (t == 0) blocksum[b] = ws[0] + ws[1] + ws[2] + ws[3];
}

// B: exclusive scan of chunk sums (single block; nb <= 1024), total -> row_start[n].
__global__ __launch_bounds__(1024) void scan_chunks(
    const int* __restrict__ blocksum, int* __restrict__ blockoff,
    int* __restrict__ row_start, int nb, int n)
{
    __shared__ int buf[2][1024];
    int t = threadIdx.x;
    int v = (t < nb) ? blocksum[t] : 0;
    int x = v;
    buf[0][t] = x;
    __syncthreads();
    int sel = 0;
    for (int off = 1; off < 1024; off <<= 1) {
        int y = (t >= off) ? buf[sel][t - off] : 0;
        x += y;
        buf[sel ^ 1][t] = x;
        sel ^= 1;
        __syncthreads();
    }
    if (t < nb) blockoff[t] = x - v;
    if (t == nb - 1) row_start[n] = x;
}

// C: within-chunk exclusive scan + chunk offset -> row_start, cursor.
__global__ __launch_bounds__(256) void scan_write(
    const int* __restrict__ deg, const int* __restrict__ blockoff,
    int* __restrict__ row_start, int* __restrict__ cursor, int n)
{
    __shared__ int buf[2][256];
    int b = blockIdx.x, t = threadIdx.x;
    int idx = b * 1024 + t * 4;
    int v0 = 0, v1 = 0, v2 = 0, v3 = 0;
    if (idx + 3 < n) {
        int4 v = *(const int4*)(deg + idx);
        v0 = v.x; v1 = v.y; v2 = v.z; v3 = v.w;
    } else if (idx < n) {
        v0 = deg[idx];
        if (idx + 1 < n) v1 = deg[idx + 1];
        if (idx + 2 < n) v2 = deg[idx + 2];
        if (idx + 3 < n) v3 = deg[idx + 3];
    }
    int s = v0 + v1 + v2 + v3;
    int x = s;
    buf[0][t] = x;
    __syncthreads();
    int sel = 0;
    for (int off = 1; off < 256; off <<= 1) {
        int y = (t >= off) ? buf[sel][t - off] : 0;
        x += y;
        buf[sel ^ 1][t] = x;
        sel ^= 1;
        __syncthreads();
    }
    int ex = x - s + blockoff[b];
    if (idx < n)     { row_start[idx] = ex;     cursor[idx] = ex;     ex += v0; }
    if (idx + 1 < n) { row_start[idx + 1] = ex; cursor[idx + 1] = ex; ex += v1; }
    if (idx + 2 < n) { row_start[idx + 2] = ex; cursor[idx + 2] = ex; ex += v2; }
    if (idx + 3 < n) { row_start[idx + 3] = ex; cursor[idx + 3] = ex; }
}

__global__ __launch_bounds__(256) void scatter_kernel(
    const int* __restrict__ src, const int* __restrict__ dst,
    int* __restrict__ cursor, int* __restrict__ col_src, int E)
{
    int e = blockIdx.x * 256 + threadIdx.x;
    if (e < E) {
        int d = dst[e];
        int pos = atomicAdd(&cursor[d], 1);
        col_src[pos] = src[e];
    }
}

// ------------------------------------------- weight convert + transpose ---
// Whi[(layer*4+which)*128 + c][k] = bf16(W[k][c]). 256 blocks: 16 mats x 16 tiles.
__global__ __launch_bounds__(256) void wcvt_kernel(
    const float* __restrict__ Wq, const float* __restrict__ Wk,
    const float* __restrict__ Wv, const float* __restrict__ Ws,
    unsigned short* __restrict__ Whi)
{
    __shared__ float lds[32][33];
    int b = blockIdx.x;
    int mat = b >> 4;          // 0..15
    int layer = mat >> 2, which = mat & 3;
    int tr = (b >> 2) & 3, tc = b & 3;
    int k0 = tr * 32, c0 = tc * 32;
    const float* Wsrc =
        (which == 0 ? Wq : which == 1 ? Wk : which == 2 ? Wv : Ws) +
        (size_t)layer * 16384;
    int t = threadIdx.x;
    #pragma unroll
    for (int i = 0; i < 4; ++i) {
        int kk = (t >> 5) + 8 * i, cc = t & 31;
        lds[kk][cc] = Wsrc[(size_t)(k0 + kk) * 128 + c0 + cc];
    }
    __syncthreads();
    #pragma unroll
    for (int i = 0; i < 4; ++i) {
        int cc = (t >> 5) + 8 * i, kk = t & 31;
        Whi[((size_t)mat * 128 + c0 + cc) * 128 + k0 + kk] = f2bf(lds[kk][cc]);
    }
}

// ---------------------------------- fp32 LN + single GEMM: hs = ln(x)@Ws+bs
// hs is error-critical (directly additive into residual stream) -> exact fp32.
__global__ __launch_bounds__(256) void lngemm_hs(
    const float* __restrict__ x, const float* __restrict__ g, const float* __restrict__ bb,
    const float* __restrict__ Ws, const float* __restrict__ bs,
    float* __restrict__ hs, int N)
{
    __shared__ float xsm[32][132];
    int t = threadIdx.x;
    int n0 = blockIdx.x * 32;
    {
        int r = t >> 3, cg = t & 7;          // 8 threads per row, 16 cols each
        int row = n0 + r;
        int rowc = row < N ? row : N - 1;
        const float* xr = x + (size_t)rowc * 128 + cg * 16;
        float4 u[4];
        #pragma unroll
        for (int i = 0; i < 4; ++i) u[i] = *(const float4*)(xr + i * 4);
        float s = 0.f, ss = 0.f;
        #pragma unroll
        for (int i = 0; i < 4; ++i) {
            s += u[i].x + u[i].y + u[i].z + u[i].w;
            ss += u[i].x * u[i].x + u[i].y * u[i].y + u[i].z * u[i].z + u[i].w * u[i].w;
        }
        s += __shfl_xor(s, 1); ss += __shfl_xor(ss, 1);
        s += __shfl_xor(s, 2); ss += __shfl_xor(ss, 2);
        s += __shfl_xor(s, 4); ss += __shfl_xor(ss, 4);
        float mu = s * (1.f / 128.f);
        float var = ss * (1.f / 128.f) - mu * mu;
        float rsv = rsqrtf(var + 1e-5f);
        const float* gp = g + cg * 16;
        const float* bp = bb + cg * 16;
        #pragma unroll
        for (int i = 0; i < 4; ++i) {
            float4 gv = *(const float4*)(gp + i * 4);
            float4 bv = *(const float4*)(bp + i * 4);
            float4 y;
            y.x = (u[i].x - mu) * rsv * gv.x + bv.x;
            y.y = (u[i].y - mu) * rsv * gv.y + bv.y;
            y.z = (u[i].z - mu) * rsv * gv.z + bv.z;
            y.w = (u[i].w - mu) * rsv * gv.w + bv.w;
            *(float4*)&xsm[r][cg * 16 + i * 4] = y;
        }
    }
    __syncthreads();

    int rg = t >> 6;           // 0..3 -> rows rg*8..rg*8+7
    int c0 = (t & 63) * 2;     // 2 cols
    float acc0[8], acc1[8];
    #pragma unroll
    for (int i = 0; i < 8; ++i) { acc0[i] = 0.f; acc1[i] = 0.f; }
    for (int k = 0; k < 128; k += 4) {
        float2 w0 = *(const float2*)(Ws + (size_t)(k + 0) * 128 + c0);
        float2 w1 = *(const float2*)(Ws + (size_t)(k + 1) * 128 + c0);
        float2 w2 = *(const float2*)(Ws + (size_t)(k + 2) * 128 + c0);
        float2 w3 = *(const float2*)(Ws + (size_t)(k + 3) * 128 + c0);
        #pragma unroll
        for (int rr = 0; rr < 8; ++rr) {
            float4 xv = *(const float4*)&xsm[rg * 8 + rr][k];
            acc0[rr] += xv.x * w0.x + xv.y * w1.x + xv.z * w2.x + xv.w * w3.x;
            acc1[rr] += xv.x * w0.y + xv.y * w1.y + xv.z * w2.y + xv.w * w3.y;
        }
    }
    float b0 = bs[c0], b1 = bs[c0 + 1];
    #pragma unroll
    for (int rr = 0; rr < 8; ++rr) {
        int row = n0 + rg * 8 + rr;
        if (row < N) {
            float2 o = make_float2(acc0[rr] + b0, acc1[rr] + b1);
            *(float2*)&hs[(size_t)row * 128 + c0] = o;
        }
    }
}

// ----------------------- plain-bf16 reg-direct MFMA: q (f32), k, v (interleaved)
// 16 rows/block, 192 thr = 3 waves; wave w -> mat w (0:q, 1:k, 2:v).
// k,v written INTERLEAVED: kv[n*256 + 2c] = k[c], kv[n*256 + 2c+1] = v[c]
// so attn gathers one 8B load per edge-lane instead of two 4B loads.
__global__ __launch_bounds__(192) void qkv_mfma(
    const float* __restrict__ x, const float* __restrict__ g, const float* __restrict__ bb,
    const unsigned short* __restrict__ Wth,   // layer slab: 4 mats x [128 cols][128 k]
    const float* __restrict__ bq, const float* __restrict__ bk, const float* __restrict__ bv,
    float* __restrict__ q, unsigned short* __restrict__ kvo, int N)
{
    __shared__ float lmu[16], lrs[16];
    int t = threadIdx.x;
    int n0 = blockIdx.x * 16;

    if (t < 128) {   // LN stats: 8 threads per row
        int r = t >> 3, cg = t & 7;
        int row = n0 + r;
        int rowc = row < N ? row : N - 1;
        const float* xr = x + (size_t)rowc * 128 + cg * 16;
        float s = 0.f, ss = 0.f;
        #pragma unroll
        for (int i = 0; i < 4; ++i) {
            float4 u = *(const float4*)(xr + i * 4);
            s += u.x + u.y + u.z + u.w;
            ss += u.x * u.x + u.y * u.y + u.z * u.z + u.w * u.w;
        }
        s += __shfl_xor(s, 1); ss += __shfl_xor(ss, 1);
        s += __shfl_xor(s, 2); ss += __shfl_xor(ss, 2);
        s += __shfl_xor(s, 4); ss += __shfl_xor(ss, 4);
        float mu = s * (1.f / 128.f);
        float var = ss * (1.f / 128.f) - mu * mu;
        float rsv = rsqrtf(var + 1e-5f);
        if (cg == 0) { lmu[r] = mu; lrs[r] = rsv; }
    }
    __syncthreads();

    int w = t >> 6;            // 0:q, 1:k, 2:v
    int l = t & 63;
    int lr = l & 15, lk = l >> 4;
    const unsigned short* Wh = Wth + (size_t)w * 16384;  // mat slab w
    int arow = n0 + lr;
    int arowc = arow < N ? arow : (N - 1);
    float mu = lmu[lr], rsv = lrs[lr];

    f32x4 acc[8];
    #pragma unroll
    for (int n = 0; n < 8; ++n) acc[n] = (f32x4){0.f, 0.f, 0.f, 0.f};

    #pragma unroll
    for (int ks = 0; ks < 4; ++ks) {
        int k0 = ks * 32 + lk * 8;
        const float* xp = x + (size_t)arowc * 128 + k0;
        short8 ah;
        #pragma unroll
        for (int jj = 0; jj < 2; ++jj) {
            float4 xv = *(const float4*)(xp + jj * 4);
            float4 gv = *(const float4*)(g + k0 + jj * 4);
            float4 bv = *(const float4*)(bb + k0 + jj * 4);
            ah[jj * 4 + 0] = (short)f2bf((xv.x - mu) * rsv * gv.x + bv.x);
            ah[jj * 4 + 1] = (short)f2bf((xv.y - mu) * rsv * gv.y + bv.y);
            ah[jj * 4 + 2] = (short)f2bf((xv.z - mu) * rsv * gv.z + bv.z);
            ah[jj * 4 + 3] = (short)f2bf((xv.w - mu) * rsv * gv.w + bv.w);
        }
        #pragma unroll
        for (int n = 0; n < 8; ++n) {
            short8 bh = *(const short8*)(Wh + (size_t)(n * 16 + lr) * 128 + k0);
            acc[n] = __builtin_amdgcn_mfma_f32_16x16x32_bf16(ah, bh, acc[n], 0, 0, 0);
        }
    }

    const float* bias = (w == 0) ? bq : (w == 1) ? bk : bv;
    #pragma unroll
    for (int n = 0; n < 8; ++n) {
        int col = n * 16 + lr;
        float bsv = bias[col];
        #pragma unroll
        for (int j = 0; j < 4; ++j) {
            int orow = n0 + lk * 4 + j;
            if (orow < N) {
                float v = acc[n][j] + bsv;
                if (w == 0) q[(size_t)orow * 128 + col] = v;
                else if (w == 1) kvo[(size_t)orow * 256 + 2 * col] = f2bf(v);
                else kvo[(size_t)orow * 256 + 2 * col + 1] = f2bf(v);
            }
        }
    }
}

// -------------------------------------------- per-node attention ----------
// One wave per dst node; lane owns channels 2l, 2l+1 (head = l/16).
// kv interleaved: one ushort4 (8B) gather per edge-lane = {k(2l),v(2l),k(2l+1),v(2l+1)}.
// No online max (scores O(+-2) after LN; max-subtraction cancels in alpha).
// xout may alias q (block 2): each wave reads q[n] before writing xout[n].
__global__ __launch_bounds__(256) void attn_kernel(
    const float* q, const unsigned short* __restrict__ kvp,
    const float* __restrict__ hs,
    const int* __restrict__ row_start, const int* __restrict__ col_src,
    const float* __restrict__ xin, float* xout, int N)
{
    int wid = threadIdx.x >> 6, lane = threadIdx.x & 63;
    int n = blockIdx.x * 4 + wid;
    if (n >= N) return;
    int c = lane * 2;
    float2 qv = *(const float2*)&q[(size_t)n * 128 + c];
    float qx = qv.x * INV_SQRT_D, qy = qv.y * INV_SQRT_D;
    int beg = row_start[n], end = row_start[n + 1];
    float den = 0.f, a0 = 0.f, a1 = 0.f;
    int i = beg;
    for (; i + 4 <= end; i += 4) {
        int s0 = col_src[i + 0];
        int s1 = col_src[i + 1];
        int s2 = col_src[i + 2];
        int s3 = col_src[i + 3];
        ushort4 kv0 = *(const ushort4*)(kvp + (size_t)s0 * 256 + 4 * lane);
        ushort4 kv1 = *(const ushort4*)(kvp + (size_t)s1 * 256 + 4 * lane);
        ushort4 kv2 = *(const ushort4*)(kvp + (size_t)s2 * 256 + 4 * lane);
        ushort4 kv3 = *(const ushort4*)(kvp + (size_t)s3 * 256 + 4 * lane);
        float p0 = qx * bf2f(kv0.x) + qy * bf2f(kv0.z);
        float p1 = qx * bf2f(kv1.x) + qy * bf2f(kv1.z);
        float p2 = qx * bf2f(kv2.x) + qy * bf2f(kv2.z);
        float p3 = qx * bf2f(kv3.x) + qy * bf2f(kv3.z);
        p0 += __shfl_xor(p0, 1); p1 += __shfl_xor(p1, 1);
        p2 += __shfl_xor(p2, 1); p3 += __shfl_xor(p3, 1);
        p0 += __shfl_xor(p0, 2); p1 += __shfl_xor(p1, 2);
        p2 += __shfl_xor(p2, 2); p3 += __shfl_xor(p3, 2);
        p0 += __shfl_xor(p0, 4); p1 += __shfl_xor(p1, 4);
        p2 += __shfl_xor(p2, 4); p3 += __shfl_xor(p3, 4);
        p0 += __shfl_xor(p0, 8); p1 += __shfl_xor(p1, 8);
        p2 += __shfl_xor(p2, 8); p3 += __shfl_xor(p3, 8);
        float w0 = __expf(p0), w1 = __expf(p1), w2 = __expf(p2), w3 = __expf(p3);
        den += (w0 + w1) + (w2 + w3);
        a0 += w0 * bf2f(kv0.y) + w1 * bf2f(kv1.y)
            + w2 * bf2f(kv2.y) + w3 * bf2f(kv3.y);
        a1 += w0 * bf2f(kv0.w) + w1 * bf2f(kv1.w)
            + w2 * bf2f(kv2.w) + w3 * bf2f(kv3.w);
    }
    for (; i < end; ++i) {
        int s = col_src[i];
        ushort4 kv = *(const ushort4*)(kvp + (size_t)s * 256 + 4 * lane);
        float p = qx * bf2f(kv.x) + qy * bf2f(kv.z);
        p += __shfl_xor(p, 1);
        p += __shfl_xor(p, 2);
        p += __shfl_xor(p, 4);
        p += __shfl_xor(p, 8);
        float w = __expf(p);
        den += w;
        a0 += w * bf2f(kv.y);
        a1 += w * bf2f(kv.w);
    }
    float inv = 1.f / (den + 1e-16f);
    float2 hv = *(const float2*)&hs[(size_t)n * 128 + c];
    float o0 = a0 * inv + hv.x;
    float o1 = a1 * inv + hv.y;
    o0 = o0 > 0.f ? o0 : 0.f;
    o1 = o1 > 0.f ? o1 : 0.f;
    float2 xv = *(const float2*)&xin[(size_t)n * 128 + c];
    xv.x += o0;
    xv.y += o1;
    *(float2*)&xout[(size_t)n * 128 + c] = xv;
}

// ------------------------------------------------------------- MLP head ---
__global__ __launch_bounds__(256) void head_kernel(
    const float* __restrict__ x, const float* __restrict__ fw,
    const float* __restrict__ fb, const float* __restrict__ ow,
    const float* __restrict__ ob, float* __restrict__ out, int OUTD, int N)
{
    int wid = threadIdx.x >> 6, lane = threadIdx.x & 63;
    int n0 = (blockIdx.x * 4 + wid) * 4;
    if (n0 >= N) return;
    float2 xr[4];
    #pragma unroll
    for (int j = 0; j < 4; ++j) {
        int n = n0 + j;
        xr[j] = (n < N) ? *(const float2*)&x[(size_t)n * 128 + lane * 2]
                        : make_float2(0.f, 0.f);
    }
    float acc[4][2];
    #pragma unroll
    for (int j = 0; j < 4; ++j) { acc[j][0] = 0.f; acc[j][1] = 0.f; }
    for (int k = 0; k < 128; ++k) {
        float w0 = fw[k * 128 + lane];
        float w1 = fw[k * 128 + 64 + lane];
        int srcl = k >> 1;
        #pragma unroll
        for (int j = 0; j < 4; ++j) {
            float xk = __shfl((k & 1) ? xr[j].y : xr[j].x, srcl);
            acc[j][0] += xk * w0;
            acc[j][1] += xk * w1;
        }
    }
    float b0 = fb[lane], b1 = fb[64 + lane];
    #pragma unroll
    for (int j = 0; j < 4; ++j) {
        int n = n0 + j;
        if (n >= N) break;  // wave-uniform
        float t0 = acc[j][0] + b0; t0 = (t0 > 0.f) ? t0 : 0.2f * t0;
        float t1 = acc[j][1] + b1; t1 = (t1 > 0.f) ? t1 : 0.2f * t1;
        for (int jo = 0; jo < OUTD; ++jo) {
            float p = t0 * ow[lane * OUTD + jo] + t1 * ow[(64 + lane) * OUTD + jo];
            p += __shfl_xor(p, 32);
            p += __shfl_xor(p, 16);
            p += __shfl_xor(p, 8);
            p += __shfl_xor(p, 4);
            p += __shfl_xor(p, 2);
            p += __shfl_xor(p, 1);
            if (lane == 0) out[(size_t)n * OUTD + jo] = p + ob[jo];
        }
    }
}

// ------------------------------------------------------------------ host --
static inline size_t align_up(size_t v, size_t a) { return (v + a - 1) & ~(a - 1); }

extern "C" void kernel_launch(void* const* d_in, const int* in_sizes, int n_in,
                              void* d_out, int out_size, void* d_ws, size_t ws_size,
                              hipStream_t stream)
{
    const float* xs = (const float*)d_in[0];
    const float* xd = (const float*)d_in[1];
    const float* xp = (const float*)d_in[2];
    const float* xt = (const float*)d_in[3];
    const int* edge = (const int*)d_in[4];
    const float* proj_w = (const float*)d_in[5];
    const float* ln_g = (const float*)d_in[6];
    const float* ln_b = (const float*)d_in[7];
    const float* Wq = (const float*)d_in[8];
    const float* bq = (const float*)d_in[9];
    const float* Wk = (const float*)d_in[10];
    const float* bk = (const float*)d_in[11];
    const float* Wv = (const float*)d_in[12];
    const float* bv = (const float*)d_in[13];
    const float* Ws = (const float*)d_in[14];
    const float* bs = (const float*)d_in[15];
    const float* fc1_w = (const float*)d_in[16];
    const float* fc1_b = (const float*)d_in[17];
    const float* fc2_w = (const float*)d_in[18];
    const float* fc2_b = (const float*)d_in[19];
    const float* fc3_w = (const float*)d_in[20];
    const float* fc3_b = (const float*)d_in[21];
    const float* fc4_w = (const float*)d_in[22];
    const float* fc4_b = (const float*)d_in[23];

    int N = in_sizes[0] / 22;
    int E = in_sizes[4] / 2;
    const int* srcp = edge;
    const int* dstp = edge + E;

    // workspace carve-up
    char* w = (char*)d_ws;
    size_t off = 0;
    auto take = [&](size_t bytes) {
        char* p = w + off;
        off = align_up(off + bytes, 256);
        return p;
    };
    float* x = (float*)take((size_t)N * 128 * 4);
    float* q = (float*)take((size_t)N * 128 * 4);
    float* hsb = (float*)take((size_t)N * 128 * 4);
    unsigned short* kvb = (unsigned short*)take((size_t)N * 256 * 2);
    unsigned short* wth = (unsigned short*)take((size_t)16 * 128 * 128 * 2);
    int* deg = (int*)take((size_t)N * 4);
    int* row_start = (int*)take((size_t)(N + 1) * 4);
    int* cursor = (int*)take((size_t)N * 4);
    int* col_src = (int*)take((size_t)E * 4);
    int* blocksum = (int*)take((size_t)1024 * 4);
    int* blockoff = (int*)take((size_t)1024 * 4);
    if (off > ws_size) {
        fprintf(stderr, "kernel_launch: ws too small (%zu > %zu)\n", off, ws_size);
        return;
    }

    float* out = (float*)d_out;

    // weight convert+transpose (bf16 [col][k], all 4 layers)
    wcvt_kernel<<<256, 256, 0, stream>>>(Wq, Wk, Wv, Ws, wth);

    // CSR build (parallel scan)
    int nb = (N + 1023) >> 10;
    hipMemsetAsync(deg, 0, (size_t)N * 4, stream);
    deg_kernel<<<(E + 255) / 256, 256, 0, stream>>>(dstp, deg, E);
    scan_reduce<<<nb, 256, 0, stream>>>(deg, blocksum, N);
    scan_chunks<<<1, 1024, 0, stream>>>(blocksum, blockoff, row_start, nb, N);
    scan_write<<<nb, 256, 0, stream>>>(deg, blockoff, row_start, cursor, N);
    scatter_kernel<<<(E + 255) / 256, 256, 0, stream>>>(srcp, dstp, cursor, col_src, E);

    // input projection
    proj_kernel<<<((size_t)N * 128 + 255) / 256, 256, 0, stream>>>(
        xs, xd, xp, xt, proj_w, x, N);

    int hs_blocks = (N + 31) / 32;
    int qkv_blocks = (N + 15) / 16;
    int attn_blocks = (N + 3) / 4;
    int head_blocks = (N + 15) / 16;

    for (int l = 0; l < 4; ++l) {
        qkv_mfma<<<qkv_blocks, 192, 0, stream>>>(
            x, ln_g + l * 128, ln_b + l * 128, wth + (size_t)l * 65536,
            bq + l * 128, bk + l * 128, bv + l * 128, q, kvb, N);
        lngemm_hs<<<hs_blocks, 256, 0, stream>>>(
            x, ln_g + l * 128, ln_b + l * 128,
            Ws + (size_t)l * 16384, bs + l * 128, hsb, N);
        if (l == 2) {
            // block 2: x_pi -> q buffer (x stays intact for block 3)
            attn_kernel<<<attn_blocks, 256, 0, stream>>>(
                q, kvb, hsb, row_start, col_src, x, q, N);
            head_kernel<<<head_blocks, 256, 0, stream>>>(
                q, fc1_w, fc1_b, fc3_w, fc3_b, out, 7, N);
        } else {
            attn_kernel<<<attn_blocks, 256, 0, stream>>>(
                q, kvb, hsb, row_start, col_src, x, x, N);
        }
    }

    // diag head from x_dg (x buffer)
    head_kernel<<<head_blocks, 256, 0, stream>>>(
        x, fc2_w, fc2_b, fc4_w, fc4_b, out + (size_t)N * 7, 3, N);
}

// Round 9
// 1513.780 us; speedup vs baseline: 1.5135x; 1.1106x over previous
//
#include <hip/hip_runtime.h>
#include <hip/hip_bf16.h>
#include <cstdio>

#define INV_SQRT_D 0.17677669529663687f

typedef __attribute__((ext_vector_type(8))) short short8;
typedef __attribute__((ext_vector_type(4))) float f32x4;

static __device__ __forceinline__ unsigned short f2bf(float f) {
    __hip_bfloat16 h = __float2bfloat16(f);
    return *reinterpret_cast<unsigned short*>(&h);
}
static __device__ __forceinline__ float bf2f(unsigned short u) {
    return __uint_as_float(((unsigned)u) << 16);
}

// ---------------------------------------------------------------- proj ----
__global__ __launch_bounds__(256) void proj_kernel(
    const float* __restrict__ xs, const float* __restrict__ xd,
    const float* __restrict__ xp, const float* __restrict__ xt,
    const float* __restrict__ W, float* __restrict__ x, int N)
{
    int idx = blockIdx.x * 256 + threadIdx.x;
    if (idx >= N * 128) return;
    int n = idx >> 7, c = idx & 127;
    const float* w = W + c;
    float acc = 0.f;
    const float* a = xs + (size_t)n * 22;
    #pragma unroll
    for (int k = 0; k < 22; ++k) acc += a[k] * w[(k) * 128];
    const float* b = xd + (size_t)n * 12;
    #pragma unroll
    for (int k = 0; k < 12; ++k) acc += b[k] * w[(22 + k) * 128];
    const float* p = xp + (size_t)n * 7;
    #pragma unroll
    for (int k = 0; k < 7; ++k) acc += p[k] * w[(34 + k) * 128];
    const float* t = xt + (size_t)n * 4;
    #pragma unroll
    for (int k = 0; k < 4; ++k) acc += t[k] * w[(41 + k) * 128];
    x[idx] = acc;
}

// ----------------------------------------------------------- CSR build ----
__global__ __launch_bounds__(256) void deg_kernel(
    const int* __restrict__ dst, int* __restrict__ deg, int E)
{
    int e = blockIdx.x * 256 + threadIdx.x;
    if (e < E) atomicAdd(&deg[dst[e]], 1);
}

// Parallel scan, 3 kernels. A: per-1024-chunk sums (int4-coalesced).
__global__ __launch_bounds__(256) void scan_reduce(
    const int* __restrict__ deg, int* __restrict__ blocksum, int n)
{
    int b = blockIdx.x, t = threadIdx.x;
    int idx = b * 1024 + t * 4;
    int s = 0;
    if (idx + 3 < n) {
        int4 v = *(const int4*)(deg + idx);
        s = v.x + v.y + v.z + v.w;
    } else if (idx < n) {
        s = deg[idx];
        if (idx + 1 < n) s += deg[idx + 1];
        if (idx + 2 < n) s += deg[idx + 2];
        if (idx + 3 < n) s += deg[idx + 3];
    }
    #pragma unroll
    for (int off = 1; off < 64; off <<= 1) s += __shfl_xor(s, off);
    __shared__ int ws[4];
    if ((t & 63) == 0) ws[t >> 6] = s;
    __syncthreads();
    if (t == 0) blocksum[b] = ws[0] + ws[1] + ws[2] + ws[3];
}

// B: exclusive scan of chunk sums (single block; nb <= 1024), total -> row_start[n].
__global__ __launch_bounds__(1024) void scan_chunks(
    const int* __restrict__ blocksum, int* __restrict__ blockoff,
    int* __restrict__ row_start, int nb, int n)
{
    __shared__ int buf[2][1024];
    int t = threadIdx.x;
    int v = (t < nb) ? blocksum[t] : 0;
    int x = v;
    buf[0][t] = x;
    __syncthreads();
    int sel = 0;
    for (int off = 1; off < 1024; off <<= 1) {
        int y = (t >= off) ? buf[sel][t - off] : 0;
        x += y;
        buf[sel ^ 1][t] = x;
        sel ^= 1;
        __syncthreads();
    }
    if (t < nb) blockoff[t] = x - v;
    if (t == nb - 1) row_start[n] = x;
}

// C: within-chunk exclusive scan + chunk offset -> row_start, cursor.
__global__ __launch_bounds__(256) void scan_write(
    const int* __restrict__ deg, const int* __restrict__ blockoff,
    int* __restrict__ row_start, int* __restrict__ cursor, int n)
{
    __shared__ int buf[2][256];
    int b = blockIdx.x, t = threadIdx.x;
    int idx = b * 1024 + t * 4;
    int v0 = 0, v1 = 0, v2 = 0, v3 = 0;
    if (idx + 3 < n) {
        int4 v = *(const int4*)(deg + idx);
        v0 = v.x; v1 = v.y; v2 = v.z; v3 = v.w;
    } else if (idx < n) {
        v0 = deg[idx];
        if (idx + 1 < n) v1 = deg[idx + 1];
        if (idx + 2 < n) v2 = deg[idx + 2];
        if (idx + 3 < n) v3 = deg[idx + 3];
    }
    int s = v0 + v1 + v2 + v3;
    int x = s;
    buf[0][t] = x;
    __syncthreads();
    int sel = 0;
    for (int off = 1; off < 256; off <<= 1) {
        int y = (t >= off) ? buf[sel][t - off] : 0;
        x += y;
        buf[sel ^ 1][t] = x;
        sel ^= 1;
        __syncthreads();
    }
    int ex = x - s + blockoff[b];
    if (idx < n)     { row_start[idx] = ex;     cursor[idx] = ex;     ex += v0; }
    if (idx + 1 < n) { row_start[idx + 1] = ex; cursor[idx + 1] = ex; ex += v1; }
    if (idx + 2 < n) { row_start[idx + 2] = ex; cursor[idx + 2] = ex; ex += v2; }
    if (idx + 3 < n) { row_start[idx + 3] = ex; cursor[idx + 3] = ex; }
}

__global__ __launch_bounds__(256) void scatter_kernel(
    const int* __restrict__ src, const int* __restrict__ dst,
    int* __restrict__ cursor, int* __restrict__ col_src, int E)
{
    int e = blockIdx.x * 256 + threadIdx.x;
    if (e < E) {
        int d = dst[e];
        int pos = atomicAdd(&cursor[d], 1);
        col_src[pos] = src[e];
    }
}

// ------------------------------------------- weight convert + transpose ---
// Whi[(layer*4+which)*128 + c][k] = bf16(W[k][c]). 256 blocks: 16 mats x 16 tiles.
__global__ __launch_bounds__(256) void wcvt_kernel(
    const float* __restrict__ Wq, const float* __restrict__ Wk,
    const float* __restrict__ Wv, const float* __restrict__ Ws,
    unsigned short* __restrict__ Whi)
{
    __shared__ float lds[32][33];
    int b = blockIdx.x;
    int mat = b >> 4;          // 0..15
    int layer = mat >> 2, which = mat & 3;
    int tr = (b >> 2) & 3, tc = b & 3;
    int k0 = tr * 32, c0 = tc * 32;
    const float* Wsrc =
        (which == 0 ? Wq : which == 1 ? Wk : which == 2 ? Wv : Ws) +
        (size_t)layer * 16384;
    int t = threadIdx.x;
    #pragma unroll
    for (int i = 0; i < 4; ++i) {
        int kk = (t >> 5) + 8 * i, cc = t & 31;
        lds[kk][cc] = Wsrc[(size_t)(k0 + kk) * 128 + c0 + cc];
    }
    __syncthreads();
    #pragma unroll
    for (int i = 0; i < 4; ++i) {
        int cc = (t >> 5) + 8 * i, kk = t & 31;
        Whi[((size_t)mat * 128 + c0 + cc) * 128 + k0 + kk] = f2bf(lds[kk][cc]);
    }
}

// ---------------------------------- fp32 LN + single GEMM: hs = ln(x)@Ws+bs
// hs is error-critical (directly additive into residual stream) -> exact fp32.
__global__ __launch_bounds__(256) void lngemm_hs(
    const float* __restrict__ x, const float* __restrict__ g, const float* __restrict__ bb,
    const float* __restrict__ Ws, const float* __restrict__ bs,
    float* __restrict__ hs, int N)
{
    __shared__ float xsm[32][132];
    int t = threadIdx.x;
    int n0 = blockIdx.x * 32;
    {
        int r = t >> 3, cg = t & 7;          // 8 threads per row, 16 cols each
        int row = n0 + r;
        int rowc = row < N ? row : N - 1;
        const float* xr = x + (size_t)rowc * 128 + cg * 16;
        float4 u[4];
        #pragma unroll
        for (int i = 0; i < 4; ++i) u[i] = *(const float4*)(xr + i * 4);
        float s = 0.f, ss = 0.f;
        #pragma unroll
        for (int i = 0; i < 4; ++i) {
            s += u[i].x + u[i].y + u[i].z + u[i].w;
            ss += u[i].x * u[i].x + u[i].y * u[i].y + u[i].z * u[i].z + u[i].w * u[i].w;
        }
        s += __shfl_xor(s, 1); ss += __shfl_xor(ss, 1);
        s += __shfl_xor(s, 2); ss += __shfl_xor(ss, 2);
        s += __shfl_xor(s, 4); ss += __shfl_xor(ss, 4);
        float mu = s * (1.f / 128.f);
        float var = ss * (1.f / 128.f) - mu * mu;
        float rsv = rsqrtf(var + 1e-5f);
        const float* gp = g + cg * 16;
        const float* bp = bb + cg * 16;
        #pragma unroll
        for (int i = 0; i < 4; ++i) {
            float4 gv = *(const float4*)(gp + i * 4);
            float4 bv = *(const float4*)(bp + i * 4);
            float4 y;
            y.x = (u[i].x - mu) * rsv * gv.x + bv.x;
            y.y = (u[i].y - mu) * rsv * gv.y + bv.y;
            y.z = (u[i].z - mu) * rsv * gv.z + bv.z;
            y.w = (u[i].w - mu) * rsv * gv.w + bv.w;
            *(float4*)&xsm[r][cg * 16 + i * 4] = y;
        }
    }
    __syncthreads();

    int rg = t >> 6;           // 0..3 -> rows rg*8..rg*8+7
    int c0 = (t & 63) * 2;     // 2 cols
    float acc0[8], acc1[8];
    #pragma unroll
    for (int i = 0; i < 8; ++i) { acc0[i] = 0.f; acc1[i] = 0.f; }
    for (int k = 0; k < 128; k += 4) {
        float2 w0 = *(const float2*)(Ws + (size_t)(k + 0) * 128 + c0);
        float2 w1 = *(const float2*)(Ws + (size_t)(k + 1) * 128 + c0);
        float2 w2 = *(const float2*)(Ws + (size_t)(k + 2) * 128 + c0);
        float2 w3 = *(const float2*)(Ws + (size_t)(k + 3) * 128 + c0);
        #pragma unroll
        for (int rr = 0; rr < 8; ++rr) {
            float4 xv = *(const float4*)&xsm[rg * 8 + rr][k];
            acc0[rr] += xv.x * w0.x + xv.y * w1.x + xv.z * w2.x + xv.w * w3.x;
            acc1[rr] += xv.x * w0.y + xv.y * w1.y + xv.z * w2.y + xv.w * w3.y;
        }
    }
    float b0 = bs[c0], b1 = bs[c0 + 1];
    #pragma unroll
    for (int rr = 0; rr < 8; ++rr) {
        int row = n0 + rg * 8 + rr;
        if (row < N) {
            float2 o = make_float2(acc0[rr] + b0, acc1[rr] + b1);
            *(float2*)&hs[(size_t)row * 128 + c0] = o;
        }
    }
}

// ----------------------- plain-bf16 reg-direct MFMA: q (f32), k, v (interleaved)
// 16 rows/block, 192 thr = 3 waves; wave w -> mat w (0:q, 1:k, 2:v).
// k,v written INTERLEAVED: kv[n*256 + 2c] = k[c], kv[n*256 + 2c+1] = v[c].
__global__ __launch_bounds__(192) void qkv_mfma(
    const float* __restrict__ x, const float* __restrict__ g, const float* __restrict__ bb,
    const unsigned short* __restrict__ Wth,   // layer slab: 4 mats x [128 cols][128 k]
    const float* __restrict__ bq, const float* __restrict__ bk, const float* __restrict__ bv,
    float* __restrict__ q, unsigned short* __restrict__ kvo, int N)
{
    __shared__ float lmu[16], lrs[16];
    int t = threadIdx.x;
    int n0 = blockIdx.x * 16;

    if (t < 128) {   // LN stats: 8 threads per row
        int r = t >> 3, cg = t & 7;
        int row = n0 + r;
        int rowc = row < N ? row : N - 1;
        const float* xr = x + (size_t)rowc * 128 + cg * 16;
        float s = 0.f, ss = 0.f;
        #pragma unroll
        for (int i = 0; i < 4; ++i) {
            float4 u = *(const float4*)(xr + i * 4);
            s += u.x + u.y + u.z + u.w;
            ss += u.x * u.x + u.y * u.y + u.z * u.z + u.w * u.w;
        }
        s += __shfl_xor(s, 1); ss += __shfl_xor(ss, 1);
        s += __shfl_xor(s, 2); ss += __shfl_xor(ss, 2);
        s += __shfl_xor(s, 4); ss += __shfl_xor(ss, 4);
        float mu = s * (1.f / 128.f);
        float var = ss * (1.f / 128.f) - mu * mu;
        float rsv = rsqrtf(var + 1e-5f);
        if (cg == 0) { lmu[r] = mu; lrs[r] = rsv; }
    }
    __syncthreads();

    int w = t >> 6;            // 0:q, 1:k, 2:v
    int l = t & 63;
    int lr = l & 15, lk = l >> 4;
    const unsigned short* Wh = Wth + (size_t)w * 16384;  // mat slab w
    int arow = n0 + lr;
    int arowc = arow < N ? arow : (N - 1);
    float mu = lmu[lr], rsv = lrs[lr];

    f32x4 acc[8];
    #pragma unroll
    for (int n = 0; n < 8; ++n) acc[n] = (f32x4){0.f, 0.f, 0.f, 0.f};

    #pragma unroll
    for (int ks = 0; ks < 4; ++ks) {
        int k0 = ks * 32 + lk * 8;
        const float* xp = x + (size_t)arowc * 128 + k0;
        short8 ah;
        #pragma unroll
        for (int jj = 0; jj < 2; ++jj) {
            float4 xv = *(const float4*)(xp + jj * 4);
            float4 gv = *(const float4*)(g + k0 + jj * 4);
            float4 bv = *(const float4*)(bb + k0 + jj * 4);
            ah[jj * 4 + 0] = (short)f2bf((xv.x - mu) * rsv * gv.x + bv.x);
            ah[jj * 4 + 1] = (short)f2bf((xv.y - mu) * rsv * gv.y + bv.y);
            ah[jj * 4 + 2] = (short)f2bf((xv.z - mu) * rsv * gv.z + bv.z);
            ah[jj * 4 + 3] = (short)f2bf((xv.w - mu) * rsv * gv.w + bv.w);
        }
        #pragma unroll
        for (int n = 0; n < 8; ++n) {
            short8 bh = *(const short8*)(Wh + (size_t)(n * 16 + lr) * 128 + k0);
            acc[n] = __builtin_amdgcn_mfma_f32_16x16x32_bf16(ah, bh, acc[n], 0, 0, 0);
        }
    }

    const float* bias = (w == 0) ? bq : (w == 1) ? bk : bv;
    #pragma unroll
    for (int n = 0; n < 8; ++n) {
        int col = n * 16 + lr;
        float bsv = bias[col];
        #pragma unroll
        for (int j = 0; j < 4; ++j) {
            int orow = n0 + lk * 4 + j;
            if (orow < N) {
                float v = acc[n][j] + bsv;
                if (w == 0) q[(size_t)orow * 128 + col] = v;
                else if (w == 1) kvo[(size_t)orow * 256 + 2 * col] = f2bf(v);
                else kvo[(size_t)orow * 256 + 2 * col + 1] = f2bf(v);
            }
        }
    }
}

// -------------------------------------------- per-node attention ----------
// One wave per dst node; lane owns channels 2l, 2l+1 (head = l/16).
// kv interleaved: one ushort4 (8B) gather per edge-lane.
// No online max (scores O(+-2) after LN; max-subtraction cancels in alpha).
// xout may alias q (block 2): each wave reads q[n] before writing xout[n].
__global__ __launch_bounds__(256) void attn_kernel(
    const float* q, const unsigned short* __restrict__ kvp,
    const float* __restrict__ hs,
    const int* __restrict__ row_start, const int* __restrict__ col_src,
    const float* __restrict__ xin, float* xout, int N)
{
    int wid = threadIdx.x >> 6, lane = threadIdx.x & 63;
    int n = blockIdx.x * 4 + wid;
    if (n >= N) return;
    int c = lane * 2;
    float2 qv = *(const float2*)&q[(size_t)n * 128 + c];
    float qx = qv.x * INV_SQRT_D, qy = qv.y * INV_SQRT_D;
    int beg = row_start[n], end = row_start[n + 1];
    float den = 0.f, a0 = 0.f, a1 = 0.f;
    int i = beg;
    for (; i + 4 <= end; i += 4) {
        int s0 = col_src[i + 0];
        int s1 = col_src[i + 1];
        int s2 = col_src[i + 2];
        int s3 = col_src[i + 3];
        ushort4 kv0 = *(const ushort4*)(kvp + (size_t)s0 * 256 + 4 * lane);
        ushort4 kv1 = *(const ushort4*)(kvp + (size_t)s1 * 256 + 4 * lane);
        ushort4 kv2 = *(const ushort4*)(kvp + (size_t)s2 * 256 + 4 * lane);
        ushort4 kv3 = *(const ushort4*)(kvp + (size_t)s3 * 256 + 4 * lane);
        float p0 = qx * bf2f(kv0.x) + qy * bf2f(kv0.z);
        float p1 = qx * bf2f(kv1.x) + qy * bf2f(kv1.z);
        float p2 = qx * bf2f(kv2.x) + qy * bf2f(kv2.z);
        float p3 = qx * bf2f(kv3.x) + qy * bf2f(kv3.z);
        p0 += __shfl_xor(p0, 1); p1 += __shfl_xor(p1, 1);
        p2 += __shfl_xor(p2, 1); p3 += __shfl_xor(p3, 1);
        p0 += __shfl_xor(p0, 2); p1 += __shfl_xor(p1, 2);
        p2 += __shfl_xor(p2, 2); p3 += __shfl_xor(p3, 2);
        p0 += __shfl_xor(p0, 4); p1 += __shfl_xor(p1, 4);
        p2 += __shfl_xor(p2, 4); p3 += __shfl_xor(p3, 4);
        p0 += __shfl_xor(p0, 8); p1 += __shfl_xor(p1, 8);
        p2 += __shfl_xor(p2, 8); p3 += __shfl_xor(p3, 8);
        float w0 = __expf(p0), w1 = __expf(p1), w2 = __expf(p2), w3 = __expf(p3);
        den += (w0 + w1) + (w2 + w3);
        a0 += w0 * bf2f(kv0.y) + w1 * bf2f(kv1.y)
            + w2 * bf2f(kv2.y) + w3 * bf2f(kv3.y);
        a1 += w0 * bf2f(kv0.w) + w1 * bf2f(kv1.w)
            + w2 * bf2f(kv2.w) + w3 * bf2f(kv3.w);
    }
    for (; i < end; ++i) {
        int s = col_src[i];
        ushort4 kv = *(const ushort4*)(kvp + (size_t)s * 256 + 4 * lane);
        float p = qx * bf2f(kv.x) + qy * bf2f(kv.z);
        p += __shfl_xor(p, 1);
        p += __shfl_xor(p, 2);
        p += __shfl_xor(p, 4);
        p += __shfl_xor(p, 8);
        float w = __expf(p);
        den += w;
        a0 += w * bf2f(kv.y);
        a1 += w * bf2f(kv.w);
    }
    float inv = 1.f / (den + 1e-16f);
    float2 hv = *(const float2*)&hs[(size_t)n * 128 + c];
    float o0 = a0 * inv + hv.x;
    float o1 = a1 * inv + hv.y;
    o0 = o0 > 0.f ? o0 : 0.f;
    o1 = o1 > 0.f ? o1 : 0.f;
    float2 xv = *(const float2*)&xin[(size_t)n * 128 + c];
    xv.x += o0;
    xv.y += o1;
    *(float2*)&xout[(size_t)n * 128 + c] = xv;
}

// ------------------------------------------------------------- MLP head ---
// GEMM-structured (lngemm_hs-style), no shfl. 32 rows/block:
//  stage x in LDS -> GEMM1 [128x128]+lrelu into LDS -> GEMM2 [128xOUTD].
__global__ __launch_bounds__(256) void head_kernel(
    const float* __restrict__ x, const float* __restrict__ fw,
    const float* __restrict__ fb, const float* __restrict__ ow,
    const float* __restrict__ ob, float* __restrict__ out, int OUTD, int N)
{
    __shared__ float xsm[32][132];
    __shared__ float tsm[32][132];
    int t = threadIdx.x;
    int n0 = blockIdx.x * 32;
    {
        int r = t >> 3, cg = t & 7;          // 8 threads/row, 16 cols each
        int row = n0 + r;
        int rowc = row < N ? row : N - 1;
        const float* xr = x + (size_t)rowc * 128 + cg * 16;
        #pragma unroll
        for (int i = 0; i < 4; ++i)
            *(float4*)&xsm[r][cg * 16 + i * 4] = *(const float4*)(xr + i * 4);
    }
    __syncthreads();

    // GEMM1: thread = 8 rows x 2 cols; +bias, leaky-relu -> tsm
    int rg = t >> 6;
    int c0 = (t & 63) * 2;
    float acc0[8], acc1[8];
    #pragma unroll
    for (int i = 0; i < 8; ++i) { acc0[i] = 0.f; acc1[i] = 0.f; }
    for (int k = 0; k < 128; k += 4) {
        float2 w0 = *(const float2*)(fw + (size_t)(k + 0) * 128 + c0);
        float2 w1 = *(const float2*)(fw + (size_t)(k + 1) * 128 + c0);
        float2 w2 = *(const float2*)(fw + (size_t)(k + 2) * 128 + c0);
        float2 w3 = *(const float2*)(fw + (size_t)(k + 3) * 128 + c0);
        #pragma unroll
        for (int rr = 0; rr < 8; ++rr) {
            float4 xv = *(const float4*)&xsm[rg * 8 + rr][k];
            acc0[rr] += xv.x * w0.x + xv.y * w1.x + xv.z * w2.x + xv.w * w3.x;
            acc1[rr] += xv.x * w0.y + xv.y * w1.y + xv.z * w2.y + xv.w * w3.y;
        }
    }
    float b0 = fb[c0], b1 = fb[c0 + 1];
    #pragma unroll
    for (int rr = 0; rr < 8; ++rr) {
        float t0 = acc0[rr] + b0; t0 = (t0 > 0.f) ? t0 : 0.2f * t0;
        float t1 = acc1[rr] + b1; t1 = (t1 > 0.f) ? t1 : 0.2f * t1;
        tsm[rg * 8 + rr][c0] = t0;
        tsm[rg * 8 + rr][c0 + 1] = t1;
    }
    __syncthreads();

    // GEMM2: thread = (row, jo); ow is L1-resident (<=3.5KB)
    int r2 = t >> 3, jo = t & 7;
    if (jo < OUTD) {
        float acc = 0.f;
        for (int k = 0; k < 128; k += 4) {
            float4 tv = *(const float4*)&tsm[r2][k];
            acc += tv.x * ow[(k + 0) * OUTD + jo];
            acc += tv.y * ow[(k + 1) * OUTD + jo];
            acc += tv.z * ow[(k + 2) * OUTD + jo];
            acc += tv.w * ow[(k + 3) * OUTD + jo];
        }
        int row = n0 + r2;
        if (row < N) out[(size_t)row * OUTD + jo] = acc + ob[jo];
    }
}

// ------------------------------------------------------------------ host --
static inline size_t align_up(size_t v, size_t a) { return (v + a - 1) & ~(a - 1); }

extern "C" void kernel_launch(void* const* d_in, const int* in_sizes, int n_in,
                              void* d_out, int out_size, void* d_ws, size_t ws_size,
                              hipStream_t stream)
{
    const float* xs = (const float*)d_in[0];
    const float* xd = (const float*)d_in[1];
    const float* xp = (const float*)d_in[2];
    const float* xt = (const float*)d_in[3];
    const int* edge = (const int*)d_in[4];
    const float* proj_w = (const float*)d_in[5];
    const float* ln_g = (const float*)d_in[6];
    const float* ln_b = (const float*)d_in[7];
    const float* Wq = (const float*)d_in[8];
    const float* bq = (const float*)d_in[9];
    const float* Wk = (const float*)d_in[10];
    const float* bk = (const float*)d_in[11];
    const float* Wv = (const float*)d_in[12];
    const float* bv = (const float*)d_in[13];
    const float* Ws = (const float*)d_in[14];
    const float* bs = (const float*)d_in[15];
    const float* fc1_w = (const float*)d_in[16];
    const float* fc1_b = (const float*)d_in[17];
    const float* fc2_w = (const float*)d_in[18];
    const float* fc2_b = (const float*)d_in[19];
    const float* fc3_w = (const float*)d_in[20];
    const float* fc3_b = (const float*)d_in[21];
    const float* fc4_w = (const float*)d_in[22];
    const float* fc4_b = (const float*)d_in[23];

    int N = in_sizes[0] / 22;
    int E = in_sizes[4] / 2;
    const int* srcp = edge;
    const int* dstp = edge + E;

    // workspace carve-up
    char* w = (char*)d_ws;
    size_t off = 0;
    auto take = [&](size_t bytes) {
        char* p = w + off;
        off = align_up(off + bytes, 256);
        return p;
    };
    float* x = (float*)take((size_t)N * 128 * 4);
    float* q = (float*)take((size_t)N * 128 * 4);
    float* hsb = (float*)take((size_t)N * 128 * 4);
    unsigned short* kvb = (unsigned short*)take((size_t)N * 256 * 2);
    unsigned short* wth = (unsigned short*)take((size_t)16 * 128 * 128 * 2);
    int* deg = (int*)take((size_t)N * 4);
    int* row_start = (int*)take((size_t)(N + 1) * 4);
    int* cursor = (int*)take((size_t)N * 4);
    int* col_src = (int*)take((size_t)E * 4);
    int* blocksum = (int*)take((size_t)1024 * 4);
    int* blockoff = (int*)take((size_t)1024 * 4);
    if (off > ws_size) {
        fprintf(stderr, "kernel_launch: ws too small (%zu > %zu)\n", off, ws_size);
        return;
    }

    float* out = (float*)d_out;

    // weight convert+transpose (bf16 [col][k], all 4 layers)
    wcvt_kernel<<<256, 256, 0, stream>>>(Wq, Wk, Wv, Ws, wth);

    // CSR build (parallel scan)
    int nb = (N + 1023) >> 10;
    hipMemsetAsync(deg, 0, (size_t)N * 4, stream);
    deg_kernel<<<(E + 255) / 256, 256, 0, stream>>>(dstp, deg, E);
    scan_reduce<<<nb, 256, 0, stream>>>(deg, blocksum, N);
    scan_chunks<<<1, 1024, 0, stream>>>(blocksum, blockoff, row_start, nb, N);
    scan_write<<<nb, 256, 0, stream>>>(deg, blockoff, row_start, cursor, N);
    scatter_kernel<<<(E + 255) / 256, 256, 0, stream>>>(srcp, dstp, cursor, col_src, E);

    // input projection
    proj_kernel<<<((size_t)N * 128 + 255) / 256, 256, 0, stream>>>(
        xs, xd, xp, xt, proj_w, x, N);

    int hs_blocks = (N + 31) / 32;
    int qkv_blocks = (N + 15) / 16;
    int attn_blocks = (N + 3) / 4;
    int head_blocks = (N + 31) / 32;

    for (int l = 0; l < 4; ++l) {
        qkv_mfma<<<qkv_blocks, 192, 0, stream>>>(
            x, ln_g + l * 128, ln_b + l * 128, wth + (size_t)l * 65536,
            bq + l * 128, bk + l * 128, bv + l * 128, q, kvb, N);
        lngemm_hs<<<hs_blocks, 256, 0, stream>>>(
            x, ln_g + l * 128, ln_b + l * 128,
            Ws + (size_t)l * 16384, bs + l * 128, hsb, N);
        if (l == 2) {
            // block 2: x_pi -> q buffer (x stays intact for block 3)
            attn_kernel<<<attn_blocks, 256, 0, stream>>>(
                q, kvb, hsb, row_start, col_src, x, q, N);
            head_kernel<<<head_blocks, 256, 0, stream>>>(
                q, fc1_w, fc1_b, fc3_w, fc3_b, out, 7, N);
        } else {
            attn_kernel<<<attn_blocks, 256, 0, stream>>>(
                q, kvb, hsb, row_start, col_src, x, x, N);
        }
    }

    // diag head from x_dg (x buffer)
    head_kernel<<<head_blocks, 256, 0, stream>>>(
        x, fc2_w, fc2_b, fc4_w, fc4_b, out + (size_t)N * 7, 3, N);
}

// Round 11
// 1441.514 us; speedup vs baseline: 1.5894x; 1.0501x over previous
//
#include <hip/hip_runtime.h>
#include <hip/hip_bf16.h>
#include <cstdio>

#define INV_SQRT_D 0.17677669529663687f

typedef __attribute__((ext_vector_type(8))) short short8;
typedef __attribute__((ext_vector_type(4))) float f32x4;

static __device__ __forceinline__ unsigned short f2bf(float f) {
    __hip_bfloat16 h = __float2bfloat16(f);
    return *reinterpret_cast<unsigned short*>(&h);
}
static __device__ __forceinline__ float bf2f(unsigned short u) {
    return __uint_as_float(((unsigned)u) << 16);
}

// ---------------------------------------------------------------- proj ----
// GEMM-structured: stage concat[45] x 32 rows in LDS, thread = 8 rows x 2 cols.
__global__ __launch_bounds__(256) void proj_kernel(
    const float* __restrict__ xs, const float* __restrict__ xd,
    const float* __restrict__ xp, const float* __restrict__ xt,
    const float* __restrict__ W, float* __restrict__ x, int N)
{
    __shared__ float xsm[32][48];
    int t = threadIdx.x;
    int n0 = blockIdx.x * 32;
    for (int idx = t; idx < 32 * 45; idx += 256) {
        int row = idx / 45, c = idx - row * 45;
        int nrow = n0 + row;
        int nr = nrow < N ? nrow : N - 1;
        float v;
        if (c < 22)      v = xs[(size_t)nr * 22 + c];
        else if (c < 34) v = xd[(size_t)nr * 12 + (c - 22)];
        else if (c < 41) v = xp[(size_t)nr * 7 + (c - 34)];
        else             v = xt[(size_t)nr * 4 + (c - 41)];
        xsm[row][c] = v;
    }
    __syncthreads();

    int rg = t >> 6;           // wave index -> rows rg*8..rg*8+7
    int c0 = (t & 63) * 2;     // 2 cols
    float acc0[8], acc1[8];
    #pragma unroll
    for (int i = 0; i < 8; ++i) { acc0[i] = 0.f; acc1[i] = 0.f; }
    for (int k = 0; k < 45; ++k) {
        float2 w = *(const float2*)(W + (size_t)k * 128 + c0);
        #pragma unroll
        for (int rr = 0; rr < 8; ++rr) {
            float xv = xsm[rg * 8 + rr][k];
            acc0[rr] += xv * w.x;
            acc1[rr] += xv * w.y;
        }
    }
    #pragma unroll
    for (int rr = 0; rr < 8; ++rr) {
        int row = n0 + rg * 8 + rr;
        if (row < N)
            *(float2*)&x[(size_t)row * 128 + c0] = make_float2(acc0[rr], acc1[rr]);
    }
}

// ----------------------------------------------------------- CSR build ----
__global__ __launch_bounds__(256) void deg_kernel(
    const int* __restrict__ dst, int* __restrict__ deg, int E)
{
    int e = blockIdx.x * 256 + threadIdx.x;
    if (e < E) atomicAdd(&deg[dst[e]], 1);
}

// Parallel scan, 3 kernels. A: per-1024-chunk sums (int4-coalesced).
__global__ __launch_bounds__(256) void scan_reduce(
    const int* __restrict__ deg, int* __restrict__ blocksum, int n)
{
    int b = blockIdx.x, t = threadIdx.x;
    int idx = b * 1024 + t * 4;
    int s = 0;
    if (idx + 3 < n) {
        int4 v = *(const int4*)(deg + idx);
        s = v.x + v.y + v.z + v.w;
    } else if (idx < n) {
        s = deg[idx];
        if (idx + 1 < n) s += deg[idx + 1];
        if (idx + 2 < n) s += deg[idx + 2];
        if (idx + 3 < n) s += deg[idx + 3];
    }
    #pragma unroll
    for (int off = 1; off < 64; off <<= 1) s += __shfl_xor(s, off);
    __shared__ int ws[4];
    if ((t & 63) == 0) ws[t >> 6] = s;
    __syncthreads();
    if (t == 0) blocksum[b] = ws[0] + ws[1] + ws[2] + ws[3];
}

// B: exclusive scan of chunk sums (single block; nb <= 1024), total -> row_start[n].
__global__ __launch_bounds__(1024) void scan_chunks(
    const int* __restrict__ blocksum, int* __restrict__ blockoff,
    int* __restrict__ row_start, int nb, int n)
{
    __shared__ int buf[2][1024];
    int t = threadIdx.x;
    int v = (t < nb) ? blocksum[t] : 0;
    int x = v;
    buf[0][t] = x;
    __syncthreads();
    int sel = 0;
    for (int off = 1; off < 1024; off <<= 1) {
        int y = (t >= off) ? buf[sel][t - off] : 0;
        x += y;
        buf[sel ^ 1][t] = x;
        sel ^= 1;
        __syncthreads();
    }
    if (t < nb) blockoff[t] = x - v;
    if (t == nb - 1) row_start[n] = x;
}

// C: within-chunk exclusive scan + chunk offset -> row_start, cursor.
__global__ __launch_bounds__(256) void scan_write(
    const int* __restrict__ deg, const int* __restrict__ blockoff,
    int* __restrict__ row_start, int* __restrict__ cursor, int n)
{
    __shared__ int buf[2][256];
    int b = blockIdx.x, t = threadIdx.x;
    int idx = b * 1024 + t * 4;
    int v0 = 0, v1 = 0, v2 = 0, v3 = 0;
    if (idx + 3 < n) {
        int4 v = *(const int4*)(deg + idx);
        v0 = v.x; v1 = v.y; v2 = v.z; v3 = v.w;
    } else if (idx < n) {
        v0 = deg[idx];
        if (idx + 1 < n) v1 = deg[idx + 1];
        if (idx + 2 < n) v2 = deg[idx + 2];
        if (idx + 3 < n) v3 = deg[idx + 3];
    }
    int s = v0 + v1 + v2 + v3;
    int x = s;
    buf[0][t] = x;
    __syncthreads();
    int sel = 0;
    for (int off = 1; off < 256; off <<= 1) {
        int y = (t >= off) ? buf[sel][t - off] : 0;
        x += y;
        buf[sel ^ 1][t] = x;
        sel ^= 1;
        __syncthreads();
    }
    int ex = x - s + blockoff[b];
    if (idx < n)     { row_start[idx] = ex;     cursor[idx] = ex;     ex += v0; }
    if (idx + 1 < n) { row_start[idx + 1] = ex; cursor[idx + 1] = ex; ex += v1; }
    if (idx + 2 < n) { row_start[idx + 2] = ex; cursor[idx + 2] = ex; ex += v2; }
    if (idx + 3 < n) { row_start[idx + 3] = ex; cursor[idx + 3] = ex; }
}

__global__ __launch_bounds__(256) void scatter_kernel(
    const int* __restrict__ src, const int* __restrict__ dst,
    int* __restrict__ cursor, int* __restrict__ col_src, int E)
{
    int e = blockIdx.x * 256 + threadIdx.x;
    if (e < E) {
        int d = dst[e];
        int pos = atomicAdd(&cursor[d], 1);
        col_src[pos] = src[e];
    }
}

// ------------------------------------------- weight convert + transpose ---
// Whi[(layer*4+which)*128 + c][k] = bf16(W[k][c]). 256 blocks: 16 mats x 16 tiles.
__global__ __launch_bounds__(256) void wcvt_kernel(
    const float* __restrict__ Wq, const float* __restrict__ Wk,
    const float* __restrict__ Wv, const float* __restrict__ Ws,
    unsigned short* __restrict__ Whi)
{
    __shared__ float lds[32][33];
    int b = blockIdx.x;
    int mat = b >> 4;          // 0..15
    int layer = mat >> 2, which = mat & 3;
    int tr = (b >> 2) & 3, tc = b & 3;
    int k0 = tr * 32, c0 = tc * 32;
    const float* Wsrc =
        (which == 0 ? Wq : which == 1 ? Wk : which == 2 ? Wv : Ws) +
        (size_t)layer * 16384;
    int t = threadIdx.x;
    #pragma unroll
    for (int i = 0; i < 4; ++i) {
        int kk = (t >> 5) + 8 * i, cc = t & 31;
        lds[kk][cc] = Wsrc[(size_t)(k0 + kk) * 128 + c0 + cc];
    }
    __syncthreads();
    #pragma unroll
    for (int i = 0; i < 4; ++i) {
        int cc = (t >> 5) + 8 * i, kk = t & 31;
        Whi[((size_t)mat * 128 + c0 + cc) * 128 + k0 + kk] = f2bf(lds[kk][cc]);
    }
}

// ---------------------------------- fp32 LN + single GEMM: hs = ln(x)@Ws+bs
// hs is error-critical (directly additive into residual stream) -> exact fp32.
__global__ __launch_bounds__(256) void lngemm_hs(
    const float* __restrict__ x, const float* __restrict__ g, const float* __restrict__ bb,
    const float* __restrict__ Ws, const float* __restrict__ bs,
    float* __restrict__ hs, int N)
{
    __shared__ float xsm[32][132];
    int t = threadIdx.x;
    int n0 = blockIdx.x * 32;
    {
        int r = t >> 3, cg = t & 7;          // 8 threads per row, 16 cols each
        int row = n0 + r;
        int rowc = row < N ? row : N - 1;
        const float* xr = x + (size_t)rowc * 128 + cg * 16;
        float4 u[4];
        #pragma unroll
        for (int i = 0; i < 4; ++i) u[i] = *(const float4*)(xr + i * 4);
        float s = 0.f, ss = 0.f;
        #pragma unroll
        for (int i = 0; i < 4; ++i) {
            s += u[i].x + u[i].y + u[i].z + u[i].w;
            ss += u[i].x * u[i].x + u[i].y * u[i].y + u[i].z * u[i].z + u[i].w * u[i].w;
        }
        s += __shfl_xor(s, 1); ss += __shfl_xor(ss, 1);
        s += __shfl_xor(s, 2); ss += __shfl_xor(ss, 2);
        s += __shfl_xor(s, 4); ss += __shfl_xor(ss, 4);
        float mu = s * (1.f / 128.f);
        float var = ss * (1.f / 128.f) - mu * mu;
        float rsv = rsqrtf(var + 1e-5f);
        const float* gp = g + cg * 16;
        const float* bp = bb + cg * 16;
        #pragma unroll
        for (int i = 0; i < 4; ++i) {
            float4 gv = *(const float4*)(gp + i * 4);
            float4 bv = *(const float4*)(bp + i * 4);
            float4 y;
            y.x = (u[i].x - mu) * rsv * gv.x + bv.x;
            y.y = (u[i].y - mu) * rsv * gv.y + bv.y;
            y.z = (u[i].z - mu) * rsv * gv.z + bv.z;
            y.w = (u[i].w - mu) * rsv * gv.w + bv.w;
            *(float4*)&xsm[r][cg * 16 + i * 4] = y;
        }
    }
    __syncthreads();

    int rg = t >> 6;           // 0..3 -> rows rg*8..rg*8+7
    int c0 = (t & 63) * 2;     // 2 cols
    float acc0[8], acc1[8];
    #pragma unroll
    for (int i = 0; i < 8; ++i) { acc0[i] = 0.f; acc1[i] = 0.f; }
    for (int k = 0; k < 128; k += 4) {
        float2 w0 = *(const float2*)(Ws + (size_t)(k + 0) * 128 + c0);
        float2 w1 = *(const float2*)(Ws + (size_t)(k + 1) * 128 + c0);
        float2 w2 = *(const float2*)(Ws + (size_t)(k + 2) * 128 + c0);
        float2 w3 = *(const float2*)(Ws + (size_t)(k + 3) * 128 + c0);
        #pragma unroll
        for (int rr = 0; rr < 8; ++rr) {
            float4 xv = *(const float4*)&xsm[rg * 8 + rr][k];
            acc0[rr] += xv.x * w0.x + xv.y * w1.x + xv.z * w2.x + xv.w * w3.x;
            acc1[rr] += xv.x * w0.y + xv.y * w1.y + xv.z * w2.y + xv.w * w3.y;
        }
    }
    float b0 = bs[c0], b1 = bs[c0 + 1];
    #pragma unroll
    for (int rr = 0; rr < 8; ++rr) {
        int row = n0 + rg * 8 + rr;
        if (row < N) {
            float2 o = make_float2(acc0[rr] + b0, acc1[rr] + b1);
            *(float2*)&hs[(size_t)row * 128 + c0] = o;
        }
    }
}

// ----------------------- plain-bf16 reg-direct MFMA: q (f32), k, v (interleaved)
// 16 rows/block, 192 thr = 3 waves; wave w -> mat w (0:q, 1:k, 2:v).
// k,v written INTERLEAVED: kv[n*256 + 2c] = k[c], kv[n*256 + 2c+1] = v[c].
__global__ __launch_bounds__(192) void qkv_mfma(
    const float* __restrict__ x, const float* __restrict__ g, const float* __restrict__ bb,
    const unsigned short* __restrict__ Wth,   // layer slab: 4 mats x [128 cols][128 k]
    const float* __restrict__ bq, const float* __restrict__ bk, const float* __restrict__ bv,
    float* __restrict__ q, unsigned short* __restrict__ kvo, int N)
{
    __shared__ float lmu[16], lrs[16];
    int t = threadIdx.x;
    int n0 = blockIdx.x * 16;

    if (t < 128) {   // LN stats: 8 threads per row
        int r = t >> 3, cg = t & 7;
        int row = n0 + r;
        int rowc = row < N ? row : N - 1;
        const float* xr = x + (size_t)rowc * 128 + cg * 16;
        float s = 0.f, ss = 0.f;
        #pragma unroll
        for (int i = 0; i < 4; ++i) {
            float4 u = *(const float4*)(xr + i * 4);
            s += u.x + u.y + u.z + u.w;
            ss += u.x * u.x + u.y * u.y + u.z * u.z + u.w * u.w;
        }
        s += __shfl_xor(s, 1); ss += __shfl_xor(ss, 1);
        s += __shfl_xor(s, 2); ss += __shfl_xor(ss, 2);
        s += __shfl_xor(s, 4); ss += __shfl_xor(ss, 4);
        float mu = s * (1.f / 128.f);
        float var = ss * (1.f / 128.f) - mu * mu;
        float rsv = rsqrtf(var + 1e-5f);
        if (cg == 0) { lmu[r] = mu; lrs[r] = rsv; }
    }
    __syncthreads();

    int w = t >> 6;            // 0:q, 1:k, 2:v
    int l = t & 63;
    int lr = l & 15, lk = l >> 4;
    const unsigned short* Wh = Wth + (size_t)w * 16384;  // mat slab w
    int arow = n0 + lr;
    int arowc = arow < N ? arow : (N - 1);
    float mu = lmu[lr], rsv = lrs[lr];

    f32x4 acc[8];
    #pragma unroll
    for (int n = 0; n < 8; ++n) acc[n] = (f32x4){0.f, 0.f, 0.f, 0.f};

    #pragma unroll
    for (int ks = 0; ks < 4; ++ks) {
        int k0 = ks * 32 + lk * 8;
        const float* xp = x + (size_t)arowc * 128 + k0;
        short8 ah;
        #pragma unroll
        for (int jj = 0; jj < 2; ++jj) {
            float4 xv = *(const float4*)(xp + jj * 4);
            float4 gv = *(const float4*)(g + k0 + jj * 4);
            float4 bv = *(const float4*)(bb + k0 + jj * 4);
            ah[jj * 4 + 0] = (short)f2bf((xv.x - mu) * rsv * gv.x + bv.x);
            ah[jj * 4 + 1] = (short)f2bf((xv.y - mu) * rsv * gv.y + bv.y);
            ah[jj * 4 + 2] = (short)f2bf((xv.z - mu) * rsv * gv.z + bv.z);
            ah[jj * 4 + 3] = (short)f2bf((xv.w - mu) * rsv * gv.w + bv.w);
        }
        #pragma unroll
        for (int n = 0; n < 8; ++n) {
            short8 bh = *(const short8*)(Wh + (size_t)(n * 16 + lr) * 128 + k0);
            acc[n] = __builtin_amdgcn_mfma_f32_16x16x32_bf16(ah, bh, acc[n], 0, 0, 0);
        }
    }

    const float* bias = (w == 0) ? bq : (w == 1) ? bk : bv;
    #pragma unroll
    for (int n = 0; n < 8; ++n) {
        int col = n * 16 + lr;
        float bsv = bias[col];
        #pragma unroll
        for (int j = 0; j < 4; ++j) {
            int orow = n0 + lk * 4 + j;
            if (orow < N) {
                float v = acc[n][j] + bsv;
                if (w == 0) q[(size_t)orow * 128 + col] = v;
                else if (w == 1) kvo[(size_t)orow * 256 + 2 * col] = f2bf(v);
                else kvo[(size_t)orow * 256 + 2 * col + 1] = f2bf(v);
            }
        }
    }
}

// -------------------------------------------- per-node attention ----------
// One wave per dst node; lane owns channels 2l, 2l+1 (head = l/16).
// kv interleaved: one ushort4 (8B) gather per edge-lane.
// No online max (scores O(+-2) after LN; max-subtraction cancels in alpha).
// xout may alias q (block 2): each wave reads q[n] before writing xout[n].
__global__ __launch_bounds__(256) void attn_kernel(
    const float* q, const unsigned short* __restrict__ kvp,
    const float* __restrict__ hs,
    const int* __restrict__ row_start, const int* __restrict__ col_src,
    const float* __restrict__ xin, float* xout, int N)
{
    int wid = threadIdx.x >> 6, lane = threadIdx.x & 63;
    int n = blockIdx.x * 4 + wid;
    if (n >= N) return;
    int c = lane * 2;
    float2 qv = *(const float2*)&q[(size_t)n * 128 + c];
    float qx = qv.x * INV_SQRT_D, qy = qv.y * INV_SQRT_D;
    int beg = row_start[n], end = row_start[n + 1];
    float den = 0.f, a0 = 0.f, a1 = 0.f;
    int i = beg;
    for (; i + 4 <= end; i += 4) {
        int s0 = col_src[i + 0];
        int s1 = col_src[i + 1];
        int s2 = col_src[i + 2];
        int s3 = col_src[i + 3];
        ushort4 kv0 = *(const ushort4*)(kvp + (size_t)s0 * 256 + 4 * lane);
        ushort4 kv1 = *(const ushort4*)(kvp + (size_t)s1 * 256 + 4 * lane);
        ushort4 kv2 = *(const ushort4*)(kvp + (size_t)s2 * 256 + 4 * lane);
        ushort4 kv3 = *(const ushort4*)(kvp + (size_t)s3 * 256 + 4 * lane);
        float p0 = qx * bf2f(kv0.x) + qy * bf2f(kv0.z);
        float p1 = qx * bf2f(kv1.x) + qy * bf2f(kv1.z);
        float p2 = qx * bf2f(kv2.x) + qy * bf2f(kv2.z);
        float p3 = qx * bf2f(kv3.x) + qy * bf2f(kv3.z);
        p0 += __shfl_xor(p0, 1); p1 += __shfl_xor(p1, 1);
        p2 += __shfl_xor(p2, 1); p3 += __shfl_xor(p3, 1);
        p0 += __shfl_xor(p0, 2); p1 += __shfl_xor(p1, 2);
        p2 += __shfl_xor(p2, 2); p3 += __shfl_xor(p3, 2);
        p0 += __shfl_xor(p0, 4); p1 += __shfl_xor(p1, 4);
        p2 += __shfl_xor(p2, 4); p3 += __shfl_xor(p3, 4);
        p0 += __shfl_xor(p0, 8); p1 += __shfl_xor(p1, 8);
        p2 += __shfl_xor(p2, 8); p3 += __shfl_xor(p3, 8);
        float w0 = __expf(p0), w1 = __expf(p1), w2 = __expf(p2), w3 = __expf(p3);
        den += (w0 + w1) + (w2 + w3);
        a0 += w0 * bf2f(kv0.y) + w1 * bf2f(kv1.y)
            + w2 * bf2f(kv2.y) + w3 * bf2f(kv3.y);
        a1 += w0 * bf2f(kv0.w) + w1 * bf2f(kv1.w)
            + w2 * bf2f(kv2.w) + w3 * bf2f(kv3.w);
    }
    for (; i < end; ++i) {
        int s = col_src[i];
        ushort4 kv = *(const ushort4*)(kvp + (size_t)s * 256 + 4 * lane);
        float p = qx * bf2f(kv.x) + qy * bf2f(kv.z);
        p += __shfl_xor(p, 1);
        p += __shfl_xor(p, 2);
        p += __shfl_xor(p, 4);
        p += __shfl_xor(p, 8);
        float w = __expf(p);
        den += w;
        a0 += w * bf2f(kv.y);
        a1 += w * bf2f(kv.w);
    }
    float inv = 1.f / (den + 1e-16f);
    float2 hv = *(const float2*)&hs[(size_t)n * 128 + c];
    float o0 = a0 * inv + hv.x;
    float o1 = a1 * inv + hv.y;
    o0 = o0 > 0.f ? o0 : 0.f;
    o1 = o1 > 0.f ? o1 : 0.f;
    float2 xv = *(const float2*)&xin[(size_t)n * 128 + c];
    xv.x += o0;
    xv.y += o1;
    *(float2*)&xout[(size_t)n * 128 + c] = xv;
}

// ------------------------------------------------------------- MLP head ---
// GEMM-structured, no shfl. 32 rows/block:
//  stage x in LDS -> GEMM1 [128x128]+lrelu into LDS -> GEMM2 [128xOUTD].
__global__ __launch_bounds__(256) void head_kernel(
    const float* __restrict__ x, const float* __restrict__ fw,
    const float* __restrict__ fb, const float* __restrict__ ow,
    const float* __restrict__ ob, float* __restrict__ out, int OUTD, int N)
{
    __shared__ float xsm[32][132];
    __shared__ float tsm[32][132];
    int t = threadIdx.x;
    int n0 = blockIdx.x * 32;
    {
        int r = t >> 3, cg = t & 7;          // 8 threads/row, 16 cols each
        int row = n0 + r;
        int rowc = row < N ? row : N - 1;
        const float* xr = x + (size_t)rowc * 128 + cg * 16;
        #pragma unroll
        for (int i = 0; i < 4; ++i)
            *(float4*)&xsm[r][cg * 16 + i * 4] = *(const float4*)(xr + i * 4);
    }
    __syncthreads();

    // GEMM1: thread = 8 rows x 2 cols; +bias, leaky-relu -> tsm
    int rg = t >> 6;
    int c0 = (t & 63) * 2;
    float acc0[8], acc1[8];
    #pragma unroll
    for (int i = 0; i < 8; ++i) { acc0[i] = 0.f; acc1[i] = 0.f; }
    for (int k = 0; k < 128; k += 4) {
        float2 w0 = *(const float2*)(fw + (size_t)(k + 0) * 128 + c0);
        float2 w1 = *(const float2*)(fw + (size_t)(k + 1) * 128 + c0);
        float2 w2 = *(const float2*)(fw + (size_t)(k + 2) * 128 + c0);
        float2 w3 = *(const float2*)(fw + (size_t)(k + 3) * 128 + c0);
        #pragma unroll
        for (int rr = 0; rr < 8; ++rr) {
            float4 xv = *(const float4*)&xsm[rg * 8 + rr][k];
            acc0[rr] += xv.x * w0.x + xv.y * w1.x + xv.z * w2.x + xv.w * w3.x;
            acc1[rr] += xv.x * w0.y + xv.y * w1.y + xv.z * w2.y + xv.w * w3.y;
        }
    }
    float b0 = fb[c0], b1 = fb[c0 + 1];
    #pragma unroll
    for (int rr = 0; rr < 8; ++rr) {
        float t0 = acc0[rr] + b0; t0 = (t0 > 0.f) ? t0 : 0.2f * t0;
        float t1 = acc1[rr] + b1; t1 = (t1 > 0.f) ? t1 : 0.2f * t1;
        tsm[rg * 8 + rr][c0] = t0;
        tsm[rg * 8 + rr][c0 + 1] = t1;
    }
    __syncthreads();

    // GEMM2: thread = (row, jo); ow is L1-resident (<=3.5KB)
    int r2 = t >> 3, jo = t & 7;
    if (jo < OUTD) {
        float acc = 0.f;
        for (int k = 0; k < 128; k += 4) {
            float4 tv = *(const float4*)&tsm[r2][k];
            acc += tv.x * ow[(k + 0) * OUTD + jo];
            acc += tv.y * ow[(k + 1) * OUTD + jo];
            acc += tv.z * ow[(k + 2) * OUTD + jo];
            acc += tv.w * ow[(k + 3) * OUTD + jo];
        }
        int row = n0 + r2;
        if (row < N) out[(size_t)row * OUTD + jo] = acc + ob[jo];
    }
}

// ------------------------------------------------------------------ host --
static inline size_t align_up(size_t v, size_t a) { return (v + a - 1) & ~(a - 1); }

extern "C" void kernel_launch(void* const* d_in, const int* in_sizes, int n_in,
                              void* d_out, int out_size, void* d_ws, size_t ws_size,
                              hipStream_t stream)
{
    const float* xs = (const float*)d_in[0];
    const float* xd = (const float*)d_in[1];
    const float* xp = (const float*)d_in[2];
    const float* xt = (const float*)d_in[3];
    const int* edge = (const int*)d_in[4];
    const float* proj_w = (const float*)d_in[5];
    const float* ln_g = (const float*)d_in[6];
    const float* ln_b = (const float*)d_in[7];
    const float* Wq = (const float*)d_in[8];
    const float* bq = (const float*)d_in[9];
    const float* Wk = (const float*)d_in[10];
    const float* bk = (const float*)d_in[11];
    const float* Wv = (const float*)d_in[12];
    const float* bv = (const float*)d_in[13];
    const float* Ws = (const float*)d_in[14];
    const float* bs = (const float*)d_in[15];
    const float* fc1_w = (const float*)d_in[16];
    const float* fc1_b = (const float*)d_in[17];
    const float* fc2_w = (const float*)d_in[18];
    const float* fc2_b = (const float*)d_in[19];
    const float* fc3_w = (const float*)d_in[20];
    const float* fc3_b = (const float*)d_in[21];
    const float* fc4_w = (const float*)d_in[22];
    const float* fc4_b = (const float*)d_in[23];

    int N = in_sizes[0] / 22;
    int E = in_sizes[4] / 2;
    const int* srcp = edge;
    const int* dstp = edge + E;

    // workspace carve-up
    char* w = (char*)d_ws;
    size_t off = 0;
    auto take = [&](size_t bytes) {
        char* p = w + off;
        off = align_up(off + bytes, 256);
        return p;
    };
    float* x = (float*)take((size_t)N * 128 * 4);
    float* q = (float*)take((size_t)N * 128 * 4);
    float* hsb = (float*)take((size_t)N * 128 * 4);
    unsigned short* kvb = (unsigned short*)take((size_t)N * 256 * 2);
    unsigned short* wth = (unsigned short*)take((size_t)16 * 128 * 128 * 2);
    int* deg = (int*)take((size_t)N * 4);
    int* row_start = (int*)take((size_t)(N + 1) * 4);
    int* cursor = (int*)take((size_t)N * 4);
    int* col_src = (int*)take((size_t)E * 4);
    int* blocksum = (int*)take((size_t)1024 * 4);
    int* blockoff = (int*)take((size_t)1024 * 4);
    if (off > ws_size) {
        fprintf(stderr, "kernel_launch: ws too small (%zu > %zu)\n", off, ws_size);
        return;
    }

    float* out = (float*)d_out;

    // weight convert+transpose (bf16 [col][k], all 4 layers)
    wcvt_kernel<<<256, 256, 0, stream>>>(Wq, Wk, Wv, Ws, wth);

    // CSR build (parallel scan)
    int nb = (N + 1023) >> 10;
    hipMemsetAsync(deg, 0, (size_t)N * 4, stream);
    deg_kernel<<<(E + 255) / 256, 256, 0, stream>>>(dstp, deg, E);
    scan_reduce<<<nb, 256, 0, stream>>>(deg, blocksum, N);
    scan_chunks<<<1, 1024, 0, stream>>>(blocksum, blockoff, row_start, nb, N);
    scan_write<<<nb, 256, 0, stream>>>(deg, blockoff, row_start, cursor, N);
    scatter_kernel<<<(E + 255) / 256, 256, 0, stream>>>(srcp, dstp, cursor, col_src, E);

    // input projection (GEMM-structured)
    proj_kernel<<<(N + 31) / 32, 256, 0, stream>>>(
        xs, xd, xp, xt, proj_w, x, N);

    int hs_blocks = (N + 31) / 32;
    int qkv_blocks = (N + 15) / 16;
    int attn_blocks = (N + 3) / 4;
    int head_blocks = (N + 31) / 32;

    for (int l = 0; l < 4; ++l) {
        qkv_mfma<<<qkv_blocks, 192, 0, stream>>>(
            x, ln_g + l * 128, ln_b + l * 128, wth + (size_t)l * 65536,
            bq + l * 128, bk + l * 128, bv + l * 128, q, kvb, N);
        lngemm_hs<<<hs_blocks, 256, 0, stream>>>(
            x, ln_g + l * 128, ln_b + l * 128,
            Ws + (size_t)l * 16384, bs + l * 128, hsb, N);
        if (l == 2) {
            // block 2: x_pi -> q buffer (x stays intact for block 3)
            attn_kernel<<<attn_blocks, 256, 0, stream>>>(
                q, kvb, hsb, row_start, col_src, x, q, N);
            head_kernel<<<head_blocks, 256, 0, stream>>>(
                q, fc1_w, fc1_b, fc3_w, fc3_b, out, 7, N);
        } else {
            attn_kernel<<<attn_blocks, 256, 0, stream>>>(
                q, kvb, hsb, row_start, col_src, x, x, N);
        }
    }

    // diag head from x_dg (x buffer)
    head_kernel<<<head_blocks, 256, 0, stream>>>(
        x, fc2_w, fc2_b, fc4_w, fc4_b, out + (size_t)N * 7, 3, N);
}

// Round 12
// 1417.763 us; speedup vs baseline: 1.6160x; 1.0168x over previous
//
#include <hip/hip_runtime.h>
#include <hip/hip_bf16.h>
#include <cstdio>

#define INV_SQRT_D 0.17677669529663687f

typedef __attribute__((ext_vector_type(8))) short short8;
typedef __attribute__((ext_vector_type(8))) unsigned short u16x8;
typedef __attribute__((ext_vector_type(4))) float f32x4;

static __device__ __forceinline__ unsigned short f2bf(float f) {
    __hip_bfloat16 h = __float2bfloat16(f);
    return *reinterpret_cast<unsigned short*>(&h);
}
static __device__ __forceinline__ float bf2f(unsigned short u) {
    return __uint_as_float(((unsigned)u) << 16);
}

// ---------------------------------------------------------------- proj ----
// GEMM-structured: stage concat[45] x 32 rows in LDS, thread = 8 rows x 2 cols.
__global__ __launch_bounds__(256) void proj_kernel(
    const float* __restrict__ xs, const float* __restrict__ xd,
    const float* __restrict__ xp, const float* __restrict__ xt,
    const float* __restrict__ W, float* __restrict__ x, int N)
{
    __shared__ float xsm[32][48];
    int t = threadIdx.x;
    int n0 = blockIdx.x * 32;
    for (int idx = t; idx < 32 * 45; idx += 256) {
        int row = idx / 45, c = idx - row * 45;
        int nrow = n0 + row;
        int nr = nrow < N ? nrow : N - 1;
        float v;
        if (c < 22)      v = xs[(size_t)nr * 22 + c];
        else if (c < 34) v = xd[(size_t)nr * 12 + (c - 22)];
        else if (c < 41) v = xp[(size_t)nr * 7 + (c - 34)];
        else             v = xt[(size_t)nr * 4 + (c - 41)];
        xsm[row][c] = v;
    }
    __syncthreads();

    int rg = t >> 6;           // wave index -> rows rg*8..rg*8+7
    int c0 = (t & 63) * 2;     // 2 cols
    float acc0[8], acc1[8];
    #pragma unroll
    for (int i = 0; i < 8; ++i) { acc0[i] = 0.f; acc1[i] = 0.f; }
    for (int k = 0; k < 45; ++k) {
        float2 w = *(const float2*)(W + (size_t)k * 128 + c0);
        #pragma unroll
        for (int rr = 0; rr < 8; ++rr) {
            float xv = xsm[rg * 8 + rr][k];
            acc0[rr] += xv * w.x;
            acc1[rr] += xv * w.y;
        }
    }
    #pragma unroll
    for (int rr = 0; rr < 8; ++rr) {
        int row = n0 + rg * 8 + rr;
        if (row < N)
            *(float2*)&x[(size_t)row * 128 + c0] = make_float2(acc0[rr], acc1[rr]);
    }
}

// ----------------------------------------------------------- CSR build ----
__global__ __launch_bounds__(256) void deg_kernel(
    const int* __restrict__ dst, int* __restrict__ deg, int E)
{
    int e = blockIdx.x * 256 + threadIdx.x;
    if (e < E) atomicAdd(&deg[dst[e]], 1);
}

// Parallel scan, 3 kernels. A: per-1024-chunk sums (int4-coalesced).
__global__ __launch_bounds__(256) void scan_reduce(
    const int* __restrict__ deg, int* __restrict__ blocksum, int n)
{
    int b = blockIdx.x, t = threadIdx.x;
    int idx = b * 1024 + t * 4;
    int s = 0;
    if (idx + 3 < n) {
        int4 v = *(const int4*)(deg + idx);
        s = v.x + v.y + v.z + v.w;
    } else if (idx < n) {
        s = deg[idx];
        if (idx + 1 < n) s += deg[idx + 1];
        if (idx + 2 < n) s += deg[idx + 2];
        if (idx + 3 < n) s += deg[idx + 3];
    }
    #pragma unroll
    for (int off = 1; off < 64; off <<= 1) s += __shfl_xor(s, off);
    __shared__ int ws[4];
    if ((t & 63) == 0) ws[t >> 6] = s;
    __syncthreads();
    if (t == 0) blocksum[b] = ws[0] + ws[1] + ws[2] + ws[3];
}

// B: exclusive scan of chunk sums (single block; nb <= 1024), total -> row_start[n].
__global__ __launch_bounds__(1024) void scan_chunks(
    const int* __restrict__ blocksum, int* __restrict__ blockoff,
    int* __restrict__ row_start, int nb, int n)
{
    __shared__ int buf[2][1024];
    int t = threadIdx.x;
    int v = (t < nb) ? blocksum[t] : 0;
    int x = v;
    buf[0][t] = x;
    __syncthreads();
    int sel = 0;
    for (int off = 1; off < 1024; off <<= 1) {
        int y = (t >= off) ? buf[sel][t - off] : 0;
        x += y;
        buf[sel ^ 1][t] = x;
        sel ^= 1;
        __syncthreads();
    }
    if (t < nb) blockoff[t] = x - v;
    if (t == nb - 1) row_start[n] = x;
}

// C: within-chunk exclusive scan + chunk offset -> row_start, cursor.
__global__ __launch_bounds__(256) void scan_write(
    const int* __restrict__ deg, const int* __restrict__ blockoff,
    int* __restrict__ row_start, int* __restrict__ cursor, int n)
{
    __shared__ int buf[2][256];
    int b = blockIdx.x, t = threadIdx.x;
    int idx = b * 1024 + t * 4;
    int v0 = 0, v1 = 0, v2 = 0, v3 = 0;
    if (idx + 3 < n) {
        int4 v = *(const int4*)(deg + idx);
        v0 = v.x; v1 = v.y; v2 = v.z; v3 = v.w;
    } else if (idx < n) {
        v0 = deg[idx];
        if (idx + 1 < n) v1 = deg[idx + 1];
        if (idx + 2 < n) v2 = deg[idx + 2];
        if (idx + 3 < n) v3 = deg[idx + 3];
    }
    int s = v0 + v1 + v2 + v3;
    int x = s;
    buf[0][t] = x;
    __syncthreads();
    int sel = 0;
    for (int off = 1; off < 256; off <<= 1) {
        int y = (t >= off) ? buf[sel][t - off] : 0;
        x += y;
        buf[sel ^ 1][t] = x;
        sel ^= 1;
        __syncthreads();
    }
    int ex = x - s + blockoff[b];
    if (idx < n)     { row_start[idx] = ex;     cursor[idx] = ex;     ex += v0; }
    if (idx + 1 < n) { row_start[idx + 1] = ex; cursor[idx + 1] = ex; ex += v1; }
    if (idx + 2 < n) { row_start[idx + 2] = ex; cursor[idx + 2] = ex; ex += v2; }
    if (idx + 3 < n) { row_start[idx + 3] = ex; cursor[idx + 3] = ex; }
}

__global__ __launch_bounds__(256) void scatter_kernel(
    const int* __restrict__ src, const int* __restrict__ dst,
    int* __restrict__ cursor, int* __restrict__ col_src, int E)
{
    int e = blockIdx.x * 256 + threadIdx.x;
    if (e < E) {
        int d = dst[e];
        int pos = atomicAdd(&cursor[d], 1);
        col_src[pos] = src[e];
    }
}

// ------------------------------------------- weight convert + transpose ---
// Whi[(layer*4+which)*128 + c][k] = bf16(W[k][c]). 256 blocks: 16 mats x 16 tiles.
__global__ __launch_bounds__(256) void wcvt_kernel(
    const float* __restrict__ Wq, const float* __restrict__ Wk,
    const float* __restrict__ Wv, const float* __restrict__ Ws,
    unsigned short* __restrict__ Whi)
{
    __shared__ float lds[32][33];
    int b = blockIdx.x;
    int mat = b >> 4;          // 0..15
    int layer = mat >> 2, which = mat & 3;
    int tr = (b >> 2) & 3, tc = b & 3;
    int k0 = tr * 32, c0 = tc * 32;
    const float* Wsrc =
        (which == 0 ? Wq : which == 1 ? Wk : which == 2 ? Wv : Ws) +
        (size_t)layer * 16384;
    int t = threadIdx.x;
    #pragma unroll
    for (int i = 0; i < 4; ++i) {
        int kk = (t >> 5) + 8 * i, cc = t & 31;
        lds[kk][cc] = Wsrc[(size_t)(k0 + kk) * 128 + c0 + cc];
    }
    __syncthreads();
    #pragma unroll
    for (int i = 0; i < 4; ++i) {
        int cc = (t >> 5) + 8 * i, kk = t & 31;
        Whi[((size_t)mat * 128 + c0 + cc) * 128 + k0 + kk] = f2bf(lds[kk][cc]);
    }
}

// ---------------------------------- fp32 LN + single GEMM: hs = ln(x)@Ws+bs
// hs is error-critical (directly additive into residual stream) -> exact fp32.
// 64 rows/block; thread = 8 rows x 4 cols (float4 weight loads).
__global__ __launch_bounds__(256) void lngemm_hs(
    const float* __restrict__ x, const float* __restrict__ g, const float* __restrict__ bb,
    const float* __restrict__ Ws, const float* __restrict__ bs,
    float* __restrict__ hs, int N)
{
    __shared__ float xsm[64][132];
    int t = threadIdx.x;
    int n0 = blockIdx.x * 64;
    {
        int r = t >> 2, cq = t & 3;          // 4 threads per row, 32 cols each
        int row = n0 + r;
        int rowc = row < N ? row : N - 1;
        const float* xr = x + (size_t)rowc * 128 + cq * 32;
        float4 u[8];
        #pragma unroll
        for (int i = 0; i < 8; ++i) u[i] = *(const float4*)(xr + i * 4);
        float s = 0.f, ss = 0.f;
        #pragma unroll
        for (int i = 0; i < 8; ++i) {
            s += u[i].x + u[i].y + u[i].z + u[i].w;
            ss += u[i].x * u[i].x + u[i].y * u[i].y + u[i].z * u[i].z + u[i].w * u[i].w;
        }
        s += __shfl_xor(s, 1); ss += __shfl_xor(ss, 1);
        s += __shfl_xor(s, 2); ss += __shfl_xor(ss, 2);
        float mu = s * (1.f / 128.f);
        float var = ss * (1.f / 128.f) - mu * mu;
        float rsv = rsqrtf(var + 1e-5f);
        const float* gp = g + cq * 32;
        const float* bp = bb + cq * 32;
        #pragma unroll
        for (int i = 0; i < 8; ++i) {
            float4 gv = *(const float4*)(gp + i * 4);
            float4 bv = *(const float4*)(bp + i * 4);
            float4 y;
            y.x = (u[i].x - mu) * rsv * gv.x + bv.x;
            y.y = (u[i].y - mu) * rsv * gv.y + bv.y;
            y.z = (u[i].z - mu) * rsv * gv.z + bv.z;
            y.w = (u[i].w - mu) * rsv * gv.w + bv.w;
            *(float4*)&xsm[r][cq * 32 + i * 4] = y;
        }
    }
    __syncthreads();

    int rg = t >> 5;           // 0..7 -> rows rg*8..rg*8+7
    int c0 = (t & 31) * 4;     // 4 cols
    float4 acc[8];
    #pragma unroll
    for (int i = 0; i < 8; ++i) acc[i] = make_float4(0.f, 0.f, 0.f, 0.f);
    for (int k = 0; k < 128; k += 4) {
        float4 w0 = *(const float4*)(Ws + (size_t)(k + 0) * 128 + c0);
        float4 w1 = *(const float4*)(Ws + (size_t)(k + 1) * 128 + c0);
        float4 w2 = *(const float4*)(Ws + (size_t)(k + 2) * 128 + c0);
        float4 w3 = *(const float4*)(Ws + (size_t)(k + 3) * 128 + c0);
        #pragma unroll
        for (int rr = 0; rr < 8; ++rr) {
            float4 xv = *(const float4*)&xsm[rg * 8 + rr][k];
            acc[rr].x += xv.x * w0.x + xv.y * w1.x + xv.z * w2.x + xv.w * w3.x;
            acc[rr].y += xv.x * w0.y + xv.y * w1.y + xv.z * w2.y + xv.w * w3.y;
            acc[rr].z += xv.x * w0.z + xv.y * w1.z + xv.z * w2.z + xv.w * w3.z;
            acc[rr].w += xv.x * w0.w + xv.y * w1.w + xv.z * w2.w + xv.w * w3.w;
        }
    }
    float4 bsv = *(const float4*)(bs + c0);
    #pragma unroll
    for (int rr = 0; rr < 8; ++rr) {
        int row = n0 + rg * 8 + rr;
        if (row < N) {
            float4 o;
            o.x = acc[rr].x + bsv.x;
            o.y = acc[rr].y + bsv.y;
            o.z = acc[rr].z + bsv.z;
            o.w = acc[rr].w + bsv.w;
            *(float4*)&hs[(size_t)row * 128 + c0] = o;
        }
    }
}

// ----------------------- plain-bf16 reg-direct MFMA: q (f32), k, v (interleaved)
// 16 rows/block, 192 thr = 3 waves; wave w -> mat w (0:q, 1:k, 2:v).
// k,v written INTERLEAVED: kv[n*256 + 2c] = k[c], kv[n*256 + 2c+1] = v[c].
__global__ __launch_bounds__(192) void qkv_mfma(
    const float* __restrict__ x, const float* __restrict__ g, const float* __restrict__ bb,
    const unsigned short* __restrict__ Wth,   // layer slab: 4 mats x [128 cols][128 k]
    const float* __restrict__ bq, const float* __restrict__ bk, const float* __restrict__ bv,
    float* __restrict__ q, unsigned short* __restrict__ kvo, int N)
{
    __shared__ float lmu[16], lrs[16];
    int t = threadIdx.x;
    int n0 = blockIdx.x * 16;

    if (t < 128) {   // LN stats: 8 threads per row
        int r = t >> 3, cg = t & 7;
        int row = n0 + r;
        int rowc = row < N ? row : N - 1;
        const float* xr = x + (size_t)rowc * 128 + cg * 16;
        float s = 0.f, ss = 0.f;
        #pragma unroll
        for (int i = 0; i < 4; ++i) {
            float4 u = *(const float4*)(xr + i * 4);
            s += u.x + u.y + u.z + u.w;
            ss += u.x * u.x + u.y * u.y + u.z * u.z + u.w * u.w;
        }
        s += __shfl_xor(s, 1); ss += __shfl_xor(ss, 1);
        s += __shfl_xor(s, 2); ss += __shfl_xor(ss, 2);
        s += __shfl_xor(s, 4); ss += __shfl_xor(ss, 4);
        float mu = s * (1.f / 128.f);
        float var = ss * (1.f / 128.f) - mu * mu;
        float rsv = rsqrtf(var + 1e-5f);
        if (cg == 0) { lmu[r] = mu; lrs[r] = rsv; }
    }
    __syncthreads();

    int w = t >> 6;            // 0:q, 1:k, 2:v
    int l = t & 63;
    int lr = l & 15, lk = l >> 4;
    const unsigned short* Wh = Wth + (size_t)w * 16384;  // mat slab w
    int arow = n0 + lr;
    int arowc = arow < N ? arow : (N - 1);
    float mu = lmu[lr], rsv = lrs[lr];

    f32x4 acc[8];
    #pragma unroll
    for (int n = 0; n < 8; ++n) acc[n] = (f32x4){0.f, 0.f, 0.f, 0.f};

    #pragma unroll
    for (int ks = 0; ks < 4; ++ks) {
        int k0 = ks * 32 + lk * 8;
        const float* xp = x + (size_t)arowc * 128 + k0;
        short8 ah;
        #pragma unroll
        for (int jj = 0; jj < 2; ++jj) {
            float4 xv = *(const float4*)(xp + jj * 4);
            float4 gv = *(const float4*)(g + k0 + jj * 4);
            float4 bv = *(const float4*)(bb + k0 + jj * 4);
            ah[jj * 4 + 0] = (short)f2bf((xv.x - mu) * rsv * gv.x + bv.x);
            ah[jj * 4 + 1] = (short)f2bf((xv.y - mu) * rsv * gv.y + bv.y);
            ah[jj * 4 + 2] = (short)f2bf((xv.z - mu) * rsv * gv.z + bv.z);
            ah[jj * 4 + 3] = (short)f2bf((xv.w - mu) * rsv * gv.w + bv.w);
        }
        #pragma unroll
        for (int n = 0; n < 8; ++n) {
            short8 bh = *(const short8*)(Wh + (size_t)(n * 16 + lr) * 128 + k0);
            acc[n] = __builtin_amdgcn_mfma_f32_16x16x32_bf16(ah, bh, acc[n], 0, 0, 0);
        }
    }

    const float* bias = (w == 0) ? bq : (w == 1) ? bk : bv;
    #pragma unroll
    for (int n = 0; n < 8; ++n) {
        int col = n * 16 + lr;
        float bsv = bias[col];
        #pragma unroll
        for (int j = 0; j < 4; ++j) {
            int orow = n0 + lk * 4 + j;
            if (orow < N) {
                float v = acc[n][j] + bsv;
                if (w == 0) q[(size_t)orow * 128 + col] = v;
                else if (w == 1) kvo[(size_t)orow * 256 + 2 * col] = f2bf(v);
                else kvo[(size_t)orow * 256 + 2 * col + 1] = f2bf(v);
            }
        }
    }
}

// -------------------------------------------- per-node attention ----------
// One wave per dst node; lane = (edge-slot eg 0..3, channel-group cg 0..15).
// Lane gathers 2x16B contiguous (8 k + 8 v channels, within head cg>>2) from
// its edge's kv row; head dot = 4-lane reduce (2 shfl); edge groups merged
// once at the end (shfl 16,32). 8-edge unroll = 4x16B in flight per lane.
// No online max (scores O(+-2) after LN; max-subtraction cancels in alpha).
// xout may alias q (block 2): q[n] is read before xout[n] is written.
__global__ __launch_bounds__(256) void attn_kernel(
    const float* q, const unsigned short* __restrict__ kvp,
    const float* __restrict__ hs,
    const int* __restrict__ row_start, const int* __restrict__ col_src,
    const float* __restrict__ xin, float* xout, int N)
{
    int wid = threadIdx.x >> 6, lane = threadIdx.x & 63;
    int n = blockIdx.x * 4 + wid;
    if (n >= N) return;
    int eg = lane >> 4;          // edge slot 0..3
    int cg = lane & 15;          // channels 8cg..8cg+7
    float qreg[8];
    {
        const float* qp = q + (size_t)n * 128 + cg * 8;
        float4 q0 = *(const float4*)qp;
        float4 q1 = *(const float4*)(qp + 4);
        qreg[0] = q0.x * INV_SQRT_D; qreg[1] = q0.y * INV_SQRT_D;
        qreg[2] = q0.z * INV_SQRT_D; qreg[3] = q0.w * INV_SQRT_D;
        qreg[4] = q1.x * INV_SQRT_D; qreg[5] = q1.y * INV_SQRT_D;
        qreg[6] = q1.z * INV_SQRT_D; qreg[7] = q1.w * INV_SQRT_D;
    }
    int beg = row_start[n], end = row_start[n + 1];
    float den = 0.f;
    float acc[8];
    #pragma unroll
    for (int j = 0; j < 8; ++j) acc[j] = 0.f;

    for (int i = beg; i < end; i += 8) {
        int e1 = i + eg, e2 = i + 4 + eg;
        int s1 = col_src[e1 < end ? e1 : beg];
        int s2 = col_src[e2 < end ? e2 : beg];
        const unsigned short* r1 = kvp + (size_t)s1 * 256 + cg * 16;
        const unsigned short* r2 = kvp + (size_t)s2 * 256 + cg * 16;
        u16x8 a1 = *(const u16x8*)r1;
        u16x8 b1 = *(const u16x8*)(r1 + 8);
        u16x8 a2 = *(const u16x8*)r2;
        u16x8 b2 = *(const u16x8*)(r2 + 8);
        float p1 = qreg[0] * bf2f(a1[0]) + qreg[1] * bf2f(a1[2])
                 + qreg[2] * bf2f(a1[4]) + qreg[3] * bf2f(a1[6])
                 + qreg[4] * bf2f(b1[0]) + qreg[5] * bf2f(b1[2])
                 + qreg[6] * bf2f(b1[4]) + qreg[7] * bf2f(b1[6]);
        float p2 = qreg[0] * bf2f(a2[0]) + qreg[1] * bf2f(a2[2])
                 + qreg[2] * bf2f(a2[4]) + qreg[3] * bf2f(a2[6])
                 + qreg[4] * bf2f(b2[0]) + qreg[5] * bf2f(b2[2])
                 + qreg[6] * bf2f(b2[4]) + qreg[7] * bf2f(b2[6]);
        p1 += __shfl_xor(p1, 1); p2 += __shfl_xor(p2, 1);
        p1 += __shfl_xor(p1, 2); p2 += __shfl_xor(p2, 2);
        float w1 = (e1 < end) ? __expf(p1) : 0.f;
        float w2 = (e2 < end) ? __expf(p2) : 0.f;
        den += w1 + w2;
        acc[0] += w1 * bf2f(a1[1]) + w2 * bf2f(a2[1]);
        acc[1] += w1 * bf2f(a1[3]) + w2 * bf2f(a2[3]);
        acc[2] += w1 * bf2f(a1[5]) + w2 * bf2f(a2[5]);
        acc[3] += w1 * bf2f(a1[7]) + w2 * bf2f(a2[7]);
        acc[4] += w1 * bf2f(b1[1]) + w2 * bf2f(b2[1]);
        acc[5] += w1 * bf2f(b1[3]) + w2 * bf2f(b2[3]);
        acc[6] += w1 * bf2f(b1[5]) + w2 * bf2f(b2[5]);
        acc[7] += w1 * bf2f(b1[7]) + w2 * bf2f(b2[7]);
    }

    den += __shfl_xor(den, 16);
    den += __shfl_xor(den, 32);
    #pragma unroll
    for (int j = 0; j < 8; ++j) {
        acc[j] += __shfl_xor(acc[j], 16);
        acc[j] += __shfl_xor(acc[j], 32);
    }

    if (eg == 0) {
        float inv = 1.f / (den + 1e-16f);
        const float* hp = hs + (size_t)n * 128 + cg * 8;
        const float* xi = xin + (size_t)n * 128 + cg * 8;
        float* xo = xout + (size_t)n * 128 + cg * 8;
        float4 h0 = *(const float4*)hp;
        float4 h1 = *(const float4*)(hp + 4);
        float4 x0 = *(const float4*)xi;
        float4 x1 = *(const float4*)(xi + 4);
        float o;
        float4 r0, r1;
        o = acc[0] * inv + h0.x; r0.x = x0.x + (o > 0.f ? o : 0.f);
        o = acc[1] * inv + h0.y; r0.y = x0.y + (o > 0.f ? o : 0.f);
        o = acc[2] * inv + h0.z; r0.z = x0.z + (o > 0.f ? o : 0.f);
        o = acc[3] * inv + h0.w; r0.w = x0.w + (o > 0.f ? o : 0.f);
        o = acc[4] * inv + h1.x; r1.x = x1.x + (o > 0.f ? o : 0.f);
        o = acc[5] * inv + h1.y; r1.y = x1.y + (o > 0.f ? o : 0.f);
        o = acc[6] * inv + h1.z; r1.z = x1.z + (o > 0.f ? o : 0.f);
        o = acc[7] * inv + h1.w; r1.w = x1.w + (o > 0.f ? o : 0.f);
        *(float4*)xo = r0;
        *(float4*)(xo + 4) = r1;
    }
}

// ------------------------------------------------------------- MLP head ---
// GEMM-structured, no shfl. 32 rows/block:
//  stage x in LDS -> GEMM1 [128x128]+lrelu into LDS -> GEMM2 [128xOUTD].
__global__ __launch_bounds__(256) void head_kernel(
    const float* __restrict__ x, const float* __restrict__ fw,
    const float* __restrict__ fb, const float* __restrict__ ow,
    const float* __restrict__ ob, float* __restrict__ out, int OUTD, int N)
{
    __shared__ float xsm[32][132];
    __shared__ float tsm[32][132];
    int t = threadIdx.x;
    int n0 = blockIdx.x * 32;
    {
        int r = t >> 3, cg = t & 7;          // 8 threads/row, 16 cols each
        int row = n0 + r;
        int rowc = row < N ? row : N - 1;
        const float* xr = x + (size_t)rowc * 128 + cg * 16;
        #pragma unroll
        for (int i = 0; i < 4; ++i)
            *(float4*)&xsm[r][cg * 16 + i * 4] = *(const float4*)(xr + i * 4);
    }
    __syncthreads();

    // GEMM1: thread = 8 rows x 2 cols; +bias, leaky-relu -> tsm
    int rg = t >> 6;
    int c0 = (t & 63) * 2;
    float acc0[8], acc1[8];
    #pragma unroll
    for (int i = 0; i < 8; ++i) { acc0[i] = 0.f; acc1[i] = 0.f; }
    for (int k = 0; k < 128; k += 4) {
        float2 w0 = *(const float2*)(fw + (size_t)(k + 0) * 128 + c0);
        float2 w1 = *(const float2*)(fw + (size_t)(k + 1) * 128 + c0);
        float2 w2 = *(const float2*)(fw + (size_t)(k + 2) * 128 + c0);
        float2 w3 = *(const float2*)(fw + (size_t)(k + 3) * 128 + c0);
        #pragma unroll
        for (int rr = 0; rr < 8; ++rr) {
            float4 xv = *(const float4*)&xsm[rg * 8 + rr][k];
            acc0[rr] += xv.x * w0.x + xv.y * w1.x + xv.z * w2.x + xv.w * w3.x;
            acc1[rr] += xv.x * w0.y + xv.y * w1.y + xv.z * w2.y + xv.w * w3.y;
        }
    }
    float b0 = fb[c0], b1 = fb[c0 + 1];
    #pragma unroll
    for (int rr = 0; rr < 8; ++rr) {
        float t0 = acc0[rr] + b0; t0 = (t0 > 0.f) ? t0 : 0.2f * t0;
        float t1 = acc1[rr] + b1; t1 = (t1 > 0.f) ? t1 : 0.2f * t1;
        tsm[rg * 8 + rr][c0] = t0;
        tsm[rg * 8 + rr][c0 + 1] = t1;
    }
    __syncthreads();

    // GEMM2: thread = (row, jo); ow is L1-resident (<=3.5KB)
    int r2 = t >> 3, jo = t & 7;
    if (jo < OUTD) {
        float acc = 0.f;
        for (int k = 0; k < 128; k += 4) {
            float4 tv = *(const float4*)&tsm[r2][k];
            acc += tv.x * ow[(k + 0) * OUTD + jo];
            acc += tv.y * ow[(k + 1) * OUTD + jo];
            acc += tv.z * ow[(k + 2) * OUTD + jo];
            acc += tv.w * ow[(k + 3) * OUTD + jo];
        }
        int row = n0 + r2;
        if (row < N) out[(size_t)row * OUTD + jo] = acc + ob[jo];
    }
}

// ------------------------------------------------------------------ host --
static inline size_t align_up(size_t v, size_t a) { return (v + a - 1) & ~(a - 1); }

extern "C" void kernel_launch(void* const* d_in, const int* in_sizes, int n_in,
                              void* d_out, int out_size, void* d_ws, size_t ws_size,
                              hipStream_t stream)
{
    const float* xs = (const float*)d_in[0];
    const float* xd = (const float*)d_in[1];
    const float* xp = (const float*)d_in[2];
    const float* xt = (const float*)d_in[3];
    const int* edge = (const int*)d_in[4];
    const float* proj_w = (const float*)d_in[5];
    const float* ln_g = (const float*)d_in[6];
    const float* ln_b = (const float*)d_in[7];
    const float* Wq = (const float*)d_in[8];
    const float* bq = (const float*)d_in[9];
    const float* Wk = (const float*)d_in[10];
    const float* bk = (const float*)d_in[11];
    const float* Wv = (const float*)d_in[12];
    const float* bv = (const float*)d_in[13];
    const float* Ws = (const float*)d_in[14];
    const float* bs = (const float*)d_in[15];
    const float* fc1_w = (const float*)d_in[16];
    const float* fc1_b = (const float*)d_in[17];
    const float* fc2_w = (const float*)d_in[18];
    const float* fc2_b = (const float*)d_in[19];
    const float* fc3_w = (const float*)d_in[20];
    const float* fc3_b = (const float*)d_in[21];
    const float* fc4_w = (const float*)d_in[22];
    const float* fc4_b = (const float*)d_in[23];

    int N = in_sizes[0] / 22;
    int E = in_sizes[4] / 2;
    const int* srcp = edge;
    const int* dstp = edge + E;

    // workspace carve-up
    char* w = (char*)d_ws;
    size_t off = 0;
    auto take = [&](size_t bytes) {
        char* p = w + off;
        off = align_up(off + bytes, 256);
        return p;
    };
    float* x = (float*)take((size_t)N * 128 * 4);
    float* q = (float*)take((size_t)N * 128 * 4);
    float* hsb = (float*)take((size_t)N * 128 * 4);
    unsigned short* kvb = (unsigned short*)take((size_t)N * 256 * 2);
    unsigned short* wth = (unsigned short*)take((size_t)16 * 128 * 128 * 2);
    int* deg = (int*)take((size_t)N * 4);
    int* row_start = (int*)take((size_t)(N + 1) * 4);
    int* cursor = (int*)take((size_t)N * 4);
    int* col_src = (int*)take((size_t)E * 4);
    int* blocksum = (int*)take((size_t)1024 * 4);
    int* blockoff = (int*)take((size_t)1024 * 4);
    if (off > ws_size) {
        fprintf(stderr, "kernel_launch: ws too small (%zu > %zu)\n", off, ws_size);
        return;
    }

    float* out = (float*)d_out;

    // weight convert+transpose (bf16 [col][k], all 4 layers)
    wcvt_kernel<<<256, 256, 0, stream>>>(Wq, Wk, Wv, Ws, wth);

    // CSR build (parallel scan)
    int nb = (N + 1023) >> 10;
    hipMemsetAsync(deg, 0, (size_t)N * 4, stream);
    deg_kernel<<<(E + 255) / 256, 256, 0, stream>>>(dstp, deg, E);
    scan_reduce<<<nb, 256, 0, stream>>>(deg, blocksum, N);
    scan_chunks<<<1, 1024, 0, stream>>>(blocksum, blockoff, row_start, nb, N);
    scan_write<<<nb, 256, 0, stream>>>(deg, blockoff, row_start, cursor, N);
    scatter_kernel<<<(E + 255) / 256, 256, 0, stream>>>(srcp, dstp, cursor, col_src, E);

    // input projection (GEMM-structured)
    proj_kernel<<<(N + 31) / 32, 256, 0, stream>>>(
        xs, xd, xp, xt, proj_w, x, N);

    int hs_blocks = (N + 63) / 64;
    int qkv_blocks = (N + 15) / 16;
    int attn_blocks = (N + 3) / 4;
    int head_blocks = (N + 31) / 32;

    for (int l = 0; l < 4; ++l) {
        qkv_mfma<<<qkv_blocks, 192, 0, stream>>>(
            x, ln_g + l * 128, ln_b + l * 128, wth + (size_t)l * 65536,
            bq + l * 128, bk + l * 128, bv + l * 128, q, kvb, N);
        lngemm_hs<<<hs_blocks, 256, 0, stream>>>(
            x, ln_g + l * 128, ln_b + l * 128,
            Ws + (size_t)l * 16384, bs + l * 128, hsb, N);
        if (l == 2) {
            // block 2: x_pi -> q buffer (x stays intact for block 3)
            attn_kernel<<<attn_blocks, 256, 0, stream>>>(
                q, kvb, hsb, row_start, col_src, x, q, N);
            head_kernel<<<head_blocks, 256, 0, stream>>>(
                q, fc1_w, fc1_b, fc3_w, fc3_b, out, 7, N);
        } else {
            attn_kernel<<<attn_blocks, 256, 0, stream>>>(
                q, kvb, hsb, row_start, col_src, x, x, N);
        }
    }

    // diag head from x_dg (x buffer)
    head_kernel<<<head_blocks, 256, 0, stream>>>(
        x, fc2_w, fc2_b, fc4_w, fc4_b, out + (size_t)N * 7, 3, N);
}